// Round 1
// baseline (895.172 us; speedup 1.0000x reference)
//
#include <hip/hip_runtime.h>
#include <math.h>

static const int cN0 = 60000;
static const int cN1 = 15000;
static const int cN2 = 3750;
static const int KNB = 32;   // neighbors
static const int PKP = 15;   // kernel points

// ---------------- L1 kpconv: Cin=1, Cout=64 ----------------
__global__ __launch_bounds__(64) void kpconv_c1(
    const float* __restrict__ qpts, const float* __restrict__ spts,
    const int* __restrict__ neigh, const float* __restrict__ feat,
    const float* __restrict__ kpts, const float* __restrict__ W,  // [15][1][64]
    float* __restrict__ out, float extent) {
  int n = blockIdx.x;
  int t = threadIdx.x;  // 64
  __shared__ float sx[32], sy[32], sz[32], sf[32];
  __shared__ float sfk[PKP];
  if (t < 32) {
    int idx = neigh[(size_t)n * 32 + t];
    sx[t] = spts[(size_t)idx * 3 + 0];
    sy[t] = spts[(size_t)idx * 3 + 1];
    sz[t] = spts[(size_t)idx * 3 + 2];
    sf[t] = feat[idx];
  }
  __syncthreads();
  float qx = qpts[(size_t)n * 3 + 0], qy = qpts[(size_t)n * 3 + 1], qz = qpts[(size_t)n * 3 + 2];
  float inv_ext = 1.0f / extent;
  if (t < PKP) {
    float kx = kpts[t * 3 + 0] * extent;
    float ky = kpts[t * 3 + 1] * extent;
    float kz = kpts[t * 3 + 2] * extent;
    float acc = 0.f;
    #pragma unroll
    for (int k = 0; k < 32; ++k) {
      float dx = sx[k] - qx - kx;
      float dy = sy[k] - qy - ky;
      float dz = sz[k] - qz - kz;
      float dist = sqrtf(dx * dx + dy * dy + dz * dz);
      float infl = fmaxf(0.f, 1.f - dist * inv_ext);
      acc += infl * sf[k];
    }
    sfk[t] = acc;
  }
  __syncthreads();
  float acc = 0.f;
  #pragma unroll
  for (int p = 0; p < PKP; ++p) acc += sfk[p] * W[p * 64 + t];
  out[(size_t)n * 64 + t] = acc > 0.f ? acc : 0.1f * acc;
}

// ---------------- neighbor aggregation: fk[n,p,c] ----------------
template <int CIN>
__global__ __launch_bounds__(256) void kpconv_agg(
    const float* __restrict__ qpts, const float* __restrict__ spts,
    const int* __restrict__ neigh, const float* __restrict__ F,
    const float* __restrict__ kpts, float* __restrict__ fkbuf,
    int r0, float extent) {
  int n = r0 + blockIdx.x;
  int t = threadIdx.x;  // 256
  __shared__ int s_idx[32];
  __shared__ float s_sp[32][3];
  __shared__ float s_infl[32][PKP];
  __shared__ float s_F[32][CIN];
  if (t < 32) {
    int idx = neigh[(size_t)n * 32 + t];
    s_idx[t] = idx;
    s_sp[t][0] = spts[(size_t)idx * 3 + 0];
    s_sp[t][1] = spts[(size_t)idx * 3 + 1];
    s_sp[t][2] = spts[(size_t)idx * 3 + 2];
  }
  __syncthreads();
  float qx = qpts[(size_t)n * 3 + 0], qy = qpts[(size_t)n * 3 + 1], qz = qpts[(size_t)n * 3 + 2];
  float inv_ext = 1.f / extent;
  for (int e = t; e < 32 * PKP; e += 256) {
    int k = e & 31, p = e >> 5;
    float dx = s_sp[k][0] - qx - kpts[p * 3 + 0] * extent;
    float dy = s_sp[k][1] - qy - kpts[p * 3 + 1] * extent;
    float dz = s_sp[k][2] - qz - kpts[p * 3 + 2] * extent;
    float dist = sqrtf(dx * dx + dy * dy + dz * dz);
    s_infl[k][p] = fmaxf(0.f, 1.f - dist * inv_ext);
  }
  for (int e = t; e < 32 * CIN; e += 256) {
    int k = e / CIN, c = e % CIN;
    s_F[k][c] = F[(size_t)s_idx[k] * CIN + c];
  }
  __syncthreads();
  for (int e = t; e < PKP * CIN; e += 256) {
    int p = e / CIN, c = e % CIN;
    float acc = 0.f;
    #pragma unroll
    for (int k = 0; k < 32; ++k) acc += s_infl[k][p] * s_F[k][c];
    fkbuf[(size_t)blockIdx.x * (PKP * CIN) + e] = acc;
  }
}

// ---------------- tiled f32 GEMM: C[M,N] = Aeff[M,KK] * B[KK,N] ----------------
// GATHER: Aeff row m = concat(A1[gidx[m]][0:K1], A2[m][0:KK-K1])
template <bool LEAKY, bool GATHER>
__global__ __launch_bounds__(256) void gemm_f32(
    const float* __restrict__ A1, const float* __restrict__ A2,
    const int* __restrict__ gidx, int K1,
    const float* __restrict__ B, float* __restrict__ C,
    int M, int N, int KK) {
  __shared__ float sA[16][65];
  __shared__ float sB[16][68];
  int t = threadIdx.x;
  int tx = t & 15, ty = t >> 4;
  int m0 = blockIdx.y * 64, n0 = blockIdx.x * 64;
  float acc[4][4] = {};
  int arow = t >> 2, acol4 = (t & 3) * 4;
  int brow = t >> 4, bcol4 = (t & 15) * 4;
  int K2 = KK - K1;
  for (int k0 = 0; k0 < KK; k0 += 16) {
    float4 av = make_float4(0.f, 0.f, 0.f, 0.f);
    int gm = m0 + arow;
    if (gm < M) {
      int kk = k0 + acol4;
      const float* src;
      if (GATHER) {
        if (kk < K1)
          src = A1 + (size_t)gidx[gm] * K1 + kk;
        else
          src = A2 + (size_t)gm * K2 + (kk - K1);
      } else {
        src = A1 + (size_t)gm * KK + kk;
      }
      av = *reinterpret_cast<const float4*>(src);
    }
    sA[acol4 + 0][arow] = av.x;
    sA[acol4 + 1][arow] = av.y;
    sA[acol4 + 2][arow] = av.z;
    sA[acol4 + 3][arow] = av.w;
    float4 bv = make_float4(0.f, 0.f, 0.f, 0.f);
    int gn = n0 + bcol4;
    if (gn < N) bv = *reinterpret_cast<const float4*>(B + (size_t)(k0 + brow) * N + gn);
    sB[brow][bcol4 + 0] = bv.x;
    sB[brow][bcol4 + 1] = bv.y;
    sB[brow][bcol4 + 2] = bv.z;
    sB[brow][bcol4 + 3] = bv.w;
    __syncthreads();
    #pragma unroll
    for (int k = 0; k < 16; ++k) {
      float a[4], b[4];
      #pragma unroll
      for (int i = 0; i < 4; ++i) a[i] = sA[k][ty * 4 + i];
      #pragma unroll
      for (int j = 0; j < 4; ++j) b[j] = sB[k][tx * 4 + j];
      #pragma unroll
      for (int i = 0; i < 4; ++i)
        #pragma unroll
        for (int j = 0; j < 4; ++j) acc[i][j] += a[i] * b[j];
    }
    __syncthreads();
  }
  int gn = n0 + tx * 4;
  if (gn < N) {
    #pragma unroll
    for (int i = 0; i < 4; ++i) {
      int m = m0 + ty * 4 + i;
      if (m < M) {
        float4 v;
        float x;
        x = acc[i][0]; v.x = (LEAKY && x < 0.f) ? 0.1f * x : x;
        x = acc[i][1]; v.y = (LEAKY && x < 0.f) ? 0.1f * x : x;
        x = acc[i][2]; v.z = (LEAKY && x < 0.f) ? 0.1f * x : x;
        x = acc[i][3]; v.w = (LEAKY && x < 0.f) ? 0.1f * x : x;
        *reinterpret_cast<float4*>(C + (size_t)m * N + gn) = v;
      }
    }
  }
}

// ---------------- global max (clamped at 0, matches padded zero row) ----------------
__global__ __launch_bounds__(256) void gmax_kernel(const float* __restrict__ x, int n,
                                                   unsigned* __restrict__ gm) {
  float m = 0.f;
  for (size_t i = (size_t)blockIdx.x * blockDim.x + threadIdx.x; i < (size_t)n;
       i += (size_t)gridDim.x * blockDim.x)
    m = fmaxf(m, x[i]);
  #pragma unroll
  for (int s = 32; s >= 1; s >>= 1) m = fmaxf(m, __shfl_xor(m, s, 64));
  __shared__ float sm[4];
  if ((threadIdx.x & 63) == 0) sm[threadIdx.x >> 6] = m;
  __syncthreads();
  if (threadIdx.x == 0) {
    float mm = fmaxf(fmaxf(sm[0], sm[1]), fmaxf(sm[2], sm[3]));
    atomicMax(gm, __float_as_uint(mm));
  }
}

// ---------------- detection scores + fnorm (C=32, one 32-lane group per point) ----------------
__global__ __launch_bounds__(256) void detect_kernel(
    const float* __restrict__ f6, const int* __restrict__ neigh,
    const float* __restrict__ gm_ptr, float* __restrict__ out_fnorm,
    float* __restrict__ out_scores, int N) {
  int grp = threadIdx.x >> 5;
  int c = threadIdx.x & 31;
  int n = blockIdx.x * 8 + grp;
  if (n >= N) return;
  float denom = gm_ptr[0] + 1e-6f;
  float fown = f6[(size_t)n * 32 + c];
  float fs = fown / denom;
  float colsum = 0.f, colmax = -INFINITY;
  int nnum = 0;
  for (int k = 0; k < 32; ++k) {
    int idx = neigh[(size_t)n * 32 + k];
    float v = f6[(size_t)idx * 32 + c] / denom;
    colsum += v;
    colmax = fmaxf(colmax, v);
    float rs = v;
    #pragma unroll
    for (int s = 16; s >= 1; s >>= 1) rs += __shfl_xor(rs, s, 32);
    if (rs != 0.f) nnum++;
  }
  if (nnum < 1) nnum = 1;
  float mean = colsum / (float)nnum;
  float x = fs - mean;
  float lms = fmaxf(x, 0.f) + log1pf(expf(-fabsf(x)));  // softplus
  float dm = fs;
  #pragma unroll
  for (int s = 16; s >= 1; s >>= 1) dm = fmaxf(dm, __shfl_xor(dm, s, 32));
  float as = lms * fs / (1e-6f + dm);
  float sc = as;
  #pragma unroll
  for (int s = 16; s >= 1; s >>= 1) sc = fmaxf(sc, __shfl_xor(sc, s, 32));
  float det = (fs == colmax) ? 1.f : 0.f;
  #pragma unroll
  for (int s = 16; s >= 1; s >>= 1) det = fmaxf(det, __shfl_xor(det, s, 32));
  float nn = fown * fown;
  #pragma unroll
  for (int s = 16; s >= 1; s >>= 1) nn += __shfl_xor(nn, s, 32);
  float inv_nrm = 1.f / fmaxf(sqrtf(nn), 1e-12f);
  out_fnorm[(size_t)n * 32 + c] = fown * inv_nrm;
  if (c == 0) out_scores[n] = sc * det;
}

extern "C" void kernel_launch(void* const* d_in, const int* in_sizes, int n_in,
                              void* d_out, int out_size, void* d_ws, size_t ws_size,
                              hipStream_t stream) {
  const float* features  = (const float*)d_in[0];
  const float* points0   = (const float*)d_in[1];
  const float* points1   = (const float*)d_in[2];
  const float* points2   = (const float*)d_in[3];
  const int* neighbors0  = (const int*)d_in[4];
  const int* neighbors1  = (const int*)d_in[5];
  const int* neighbors2  = (const int*)d_in[6];
  const int* pools0      = (const int*)d_in[7];
  const int* pools1      = (const int*)d_in[8];
  const int* upsamples0  = (const int*)d_in[9];
  const int* upsamples1  = (const int*)d_in[10];
  const float* kpoints   = (const float*)d_in[11];
  const float* W1  = (const float*)d_in[12];
  const float* W2  = (const float*)d_in[13];
  const float* W3  = (const float*)d_in[14];
  const float* W4  = (const float*)d_in[15];
  const float* W5  = (const float*)d_in[16];
  const float* Wu1 = (const float*)d_in[17];
  const float* Wu2 = (const float*)d_in[18];

  const float R0 = 0.5f;

  float* ws = (float*)d_ws;
  float* f0 = ws;                        // N0*64
  float* f1 = f0 + (size_t)cN0 * 64;     // N1*64
  float* f2 = f1 + (size_t)cN1 * 64;     // N1*128
  float* f3 = f2 + (size_t)cN1 * 128;    // N2*128
  float* f4 = f3 + (size_t)cN2 * 128;    // N2*256
  float* f5 = f4 + (size_t)cN2 * 256;    // N1*128
  float* f6 = f5 + (size_t)cN1 * 128;    // N0*32
  unsigned* gm = (unsigned*)(f6 + (size_t)cN0 * 32);
  float* fk = (float*)(gm + 4);          // up to 7500*960 = 7.2M floats

  // ---- L1: simple kpconv, Cin=1 -> 64 ----
  kpconv_c1<<<cN0, 64, 0, stream>>>(points0, points0, neighbors0, features, kpoints, W1, f0, R0);

  const int CH = 7500;
  // ---- L2: strided, f0 -> f1 [N1,64], extent R0 ----
  for (int r0 = 0; r0 < cN1; r0 += CH) {
    int cnt = (cN1 - r0 < CH) ? (cN1 - r0) : CH;
    kpconv_agg<64><<<cnt, 256, 0, stream>>>(points1, points0, pools0, f0, kpoints, fk, r0, R0);
    dim3 g(1, (cnt + 63) / 64);
    gemm_f32<true, false><<<g, 256, 0, stream>>>(fk, nullptr, nullptr, 960, W2,
                                                 f1 + (size_t)r0 * 64, cnt, 64, 960);
  }
  // ---- L3: simple, f1 -> f2 [N1,128], extent 2*R0 ----
  for (int r0 = 0; r0 < cN1; r0 += CH) {
    int cnt = (cN1 - r0 < CH) ? (cN1 - r0) : CH;
    kpconv_agg<64><<<cnt, 256, 0, stream>>>(points1, points1, neighbors1, f1, kpoints, fk, r0, 2.f * R0);
    dim3 g(2, (cnt + 63) / 64);
    gemm_f32<true, false><<<g, 256, 0, stream>>>(fk, nullptr, nullptr, 960, W3,
                                                 f2 + (size_t)r0 * 128, cnt, 128, 960);
  }
  // ---- L4: strided, f2 -> f3 [N2,128], extent 2*R0 ----
  {
    kpconv_agg<128><<<cN2, 256, 0, stream>>>(points2, points1, pools1, f2, kpoints, fk, 0, 2.f * R0);
    dim3 g(2, (cN2 + 63) / 64);
    gemm_f32<true, false><<<g, 256, 0, stream>>>(fk, nullptr, nullptr, 1920, W4, f3, cN2, 128, 1920);
  }
  // ---- L5: simple, f3 -> f4 [N2,256], extent 4*R0 ----
  {
    kpconv_agg<128><<<cN2, 256, 0, stream>>>(points2, points2, neighbors2, f3, kpoints, fk, 0, 4.f * R0);
    dim3 g(4, (cN2 + 63) / 64);
    gemm_f32<true, false><<<g, 256, 0, stream>>>(fk, nullptr, nullptr, 1920, W5, f4, cN2, 256, 1920);
  }
  // ---- decoder 1: f5 = leaky(concat(f4[up1], f2) @ Wu1) [N1,128] ----
  {
    dim3 g(2, (cN1 + 63) / 64);
    gemm_f32<true, true><<<g, 256, 0, stream>>>(f4, f2, upsamples1, 256, Wu1, f5, cN1, 128, 384);
  }
  // ---- decoder 2: f6 = concat(f5[up0], f0) @ Wu2 [N0,32] ----
  {
    dim3 g(1, (cN0 + 63) / 64);
    gemm_f32<false, true><<<g, 256, 0, stream>>>(f5, f0, upsamples0, 128, Wu2, f6, cN0, 32, 192);
  }
  // ---- detection scores + fnorm ----
  hipMemsetAsync(gm, 0, 4, stream);
  gmax_kernel<<<1024, 256, 0, stream>>>(f6, cN0 * 32, gm);
  float* out_fnorm = (float*)d_out;
  float* out_scores = out_fnorm + (size_t)cN0 * 32;
  detect_kernel<<<(cN0 + 7) / 8, 256, 0, stream>>>(f6, neighbors0, (const float*)gm,
                                                   out_fnorm, out_scores, cN0);
}

// Round 2
// 326.655 us; speedup vs baseline: 2.7404x; 2.7404x over previous
//
#include <hip/hip_runtime.h>
#include <math.h>

static const int cN0 = 60000;
static const int cN1 = 15000;
static const int cN2 = 3750;

typedef __bf16 bf16x8 __attribute__((ext_vector_type(8)));
typedef float f32x4 __attribute__((ext_vector_type(4)));

#define GLOAD_LDS16(gsrc, ldst)                                                        \
  __builtin_amdgcn_global_load_lds((const __attribute__((address_space(1))) void*)(gsrc), \
                                   (__attribute__((address_space(3))) void*)(ldst), 16, 0, 0)

// ---------------- weight convert + transpose: WT[N][K] bf16 from W[K][N] f32 ----------------
__global__ __launch_bounds__(256) void convert_wt(
    const float* __restrict__ W2, const float* __restrict__ W3, const float* __restrict__ W4,
    const float* __restrict__ W5, const float* __restrict__ Wu1, const float* __restrict__ Wu2,
    __bf16* __restrict__ T2, __bf16* __restrict__ T3, __bf16* __restrict__ T4,
    __bf16* __restrict__ T5, __bf16* __restrict__ Tu1, __bf16* __restrict__ Tu2) {
  int which = blockIdx.y;
  const float* src;
  __bf16* dst;
  int Kd, Nd;
  switch (which) {
    case 0: src = W2;  dst = T2;  Kd = 960;  Nd = 64;  break;
    case 1: src = W3;  dst = T3;  Kd = 960;  Nd = 128; break;
    case 2: src = W4;  dst = T4;  Kd = 1920; Nd = 128; break;
    case 3: src = W5;  dst = T5;  Kd = 1920; Nd = 256; break;
    case 4: src = Wu1; dst = Tu1; Kd = 384;  Nd = 128; break;
    default: src = Wu2; dst = Tu2; Kd = 192; Nd = 32;  break;
  }
  int total = Kd * Nd;
  for (int e = blockIdx.x * 256 + threadIdx.x; e < total; e += gridDim.x * 256) {
    int n = e / Kd, k = e % Kd;
    dst[e] = (__bf16)src[(size_t)k * Nd + n];
  }
}

// ---------------- L1 kpconv: Cin=1 -> 64, wave per point ----------------
__global__ __launch_bounds__(256) void kpconv_l1(
    const float* __restrict__ pts, const int* __restrict__ neigh,
    const float* __restrict__ feat, const float* __restrict__ kpts,
    const float* __restrict__ W1, __bf16* __restrict__ f0, float extent) {
  int n = blockIdx.x * 4 + (threadIdx.x >> 6);
  int l = threadIdx.x & 63;
  float px = 0.f, py = 0.f, pz = 0.f, fv = 0.f;
  if (l < 32) {
    int idx = neigh[(size_t)n * 32 + l];
    px = pts[(size_t)idx * 3 + 0];
    py = pts[(size_t)idx * 3 + 1];
    pz = pts[(size_t)idx * 3 + 2];
    fv = feat[idx];
  }
  float qx = pts[(size_t)n * 3 + 0], qy = pts[(size_t)n * 3 + 1], qz = pts[(size_t)n * 3 + 2];
  int p = l < 15 ? l : 0;
  float kx = qx + kpts[p * 3 + 0] * extent;
  float ky = qy + kpts[p * 3 + 1] * extent;
  float kz = qz + kpts[p * 3 + 2] * extent;
  float inv = 1.f / extent;
  float fk = 0.f;
  #pragma unroll 8
  for (int k = 0; k < 32; ++k) {
    float sx = __shfl(px, k, 64) - kx;
    float sy = __shfl(py, k, 64) - ky;
    float sz = __shfl(pz, k, 64) - kz;
    float sf = __shfl(fv, k, 64);
    float d = sqrtf(sx * sx + sy * sy + sz * sz);
    fk += fmaxf(0.f, 1.f - d * inv) * sf;
  }
  float o = 0.f;
  #pragma unroll
  for (int pp = 0; pp < 15; ++pp) o += __shfl(fk, pp, 64) * W1[pp * 64 + l];
  o = o > 0.f ? o : 0.1f * o;
  f0[(size_t)n * 64 + l] = (__bf16)o;
}

// ---------------- neighbor aggregation: fkb[n, p*CIN+c] bf16, 2 points/block ----------------
template <int CIN>
__global__ __launch_bounds__(256) void kpconv_agg(
    const float* __restrict__ qpts, const float* __restrict__ spts,
    const int* __restrict__ neigh, const __bf16* __restrict__ F,
    const float* __restrict__ kpts, __bf16* __restrict__ fkb,
    int M, float extent) {
  constexpr int CPR = CIN / 8;  // 16B chunks per F row
  const int pt = threadIdx.x >> 7;
  const int st = threadIdx.x & 127;
  const int n = blockIdx.x * 2 + pt;
  __shared__ int s_idx[2][32];
  __shared__ float s_infl[2][32][16];
  __shared__ __bf16 s_F[2][32][CIN];
  float inv = 1.f / extent;
  float qx = qpts[(size_t)n * 3 + 0], qy = qpts[(size_t)n * 3 + 1], qz = qpts[(size_t)n * 3 + 2];
  if (st < 32) {
    int idx = neigh[(size_t)n * 32 + st];
    s_idx[pt][st] = idx;
    float sx = spts[(size_t)idx * 3 + 0] - qx;
    float sy = spts[(size_t)idx * 3 + 1] - qy;
    float sz = spts[(size_t)idx * 3 + 2] - qz;
    #pragma unroll
    for (int p = 0; p < 15; ++p) {
      float dx = sx - kpts[p * 3 + 0] * extent;
      float dy = sy - kpts[p * 3 + 1] * extent;
      float dz = sz - kpts[p * 3 + 2] * extent;
      float d = sqrtf(dx * dx + dy * dy + dz * dz);
      s_infl[pt][st][p] = fmaxf(0.f, 1.f - d * inv);
    }
  }
  __syncthreads();
  #pragma unroll
  for (int ch = st; ch < 32 * CPR; ch += 128) {
    int k = ch / CPR, c8 = ch % CPR;
    *(bf16x8*)&s_F[pt][k][c8 * 8] = *(const bf16x8*)(F + (size_t)s_idx[pt][k] * CIN + c8 * 8);
  }
  __syncthreads();
  int p = st >> 3, cb = st & 7;
  if (p < 15) {
    constexpr int CW = CIN / 8;  // cols per thread
    const int c0 = cb * CW;
    float acc[CW];
    #pragma unroll
    for (int j = 0; j < CW; ++j) acc[j] = 0.f;
    #pragma unroll 4
    for (int k = 0; k < 32; ++k) {
      float w = s_infl[pt][k][p];
      #pragma unroll
      for (int v = 0; v < CW / 8; ++v) {
        bf16x8 fv = *(const bf16x8*)&s_F[pt][k][c0 + v * 8];
        #pragma unroll
        for (int j = 0; j < 8; ++j) acc[v * 8 + j] += w * (float)fv[j];
      }
    }
    size_t obase = (size_t)n * (15 * CIN) + p * CIN + c0;
    #pragma unroll
    for (int v = 0; v < CW / 8; ++v) {
      bf16x8 ov;
      #pragma unroll
      for (int j = 0; j < 8; ++j) ov[j] = (__bf16)acc[v * 8 + j];
      *(bf16x8*)&fkb[obase + v * 8] = ov;
    }
  }
}

// ---------------- MFMA bf16 GEMM: C[M,N] = Aeff[M,KK] * BT[N,KK]^T ----------------
// GATHER: Aeff row m = concat(A1[gidx[m]][0:K1], A2[m][0:KK-K1]). BK=64, tile 64x64.
template <bool LEAKY, bool GATHER, bool OUTF32>
__global__ __launch_bounds__(256, 2) void gemm_mfma(
    const __bf16* __restrict__ A1, const __bf16* __restrict__ A2,
    const int* __restrict__ gidx, const int K1,
    const __bf16* __restrict__ BT, void* __restrict__ Cout,
    const int M, const int N, const int KK) {
  __shared__ __bf16 sA[2][4096];
  __shared__ __bf16 sB[2][4096];
  const int t = threadIdx.x;
  const int lane = t & 63, wave = t >> 6;
  const int wr = wave >> 1, wc = wave & 1;
  const int m0 = blockIdx.y * 64, n0 = blockIdx.x * 64;
  const int K2 = KK - K1;

  // staging geometry: slot = r*256 + wave*64 + lane; row=slot>>3, dst chunk=slot&7,
  // src chunk = dst ^ (row&7)  (XOR swizzle applied on the SOURCE; LDS dest linear)
  const __bf16* a1row[2];
  const __bf16* a2row[2];
  const __bf16* brow_[2];
  int csrc[2], wbase[2];
  #pragma unroll
  for (int r = 0; r < 2; ++r) {
    int slot = r * 256 + wave * 64 + lane;
    int row = slot >> 3;
    csrc[r] = ((slot & 7) ^ (row & 7)) * 8;
    wbase[r] = (r * 256 + wave * 64) * 8;
    int gm = m0 + row; if (gm > M - 1) gm = M - 1;
    if (GATHER) {
      a1row[r] = A1 + (size_t)gidx[gm] * K1;
      a2row[r] = A2 + (size_t)gm * (size_t)K2;
    } else {
      a1row[r] = A1 + (size_t)gm * (size_t)KK;
    }
    int gn = n0 + row; if (gn > N - 1) gn = N - 1;
    brow_[r] = BT + (size_t)gn * (size_t)KK;
  }

  // fragment LDS offsets (read with the same XOR swizzle)
  int offA[2][2], offB[2][2];
  #pragma unroll
  for (int i = 0; i < 2; ++i)
    #pragma unroll
    for (int s = 0; s < 2; ++s) {
      int ra = wr * 32 + i * 16 + (lane & 15);
      int rb = wc * 32 + i * 16 + (lane & 15);
      int ch = s * 4 + (lane >> 4);
      offA[i][s] = ra * 64 + (ch ^ (ra & 7)) * 8;
      offB[i][s] = rb * 64 + (ch ^ (rb & 7)) * 8;
    }

  f32x4 acc[2][2];
  #pragma unroll
  for (int i = 0; i < 2; ++i)
    #pragma unroll
    for (int j = 0; j < 2; ++j) acc[i][j] = (f32x4){0.f, 0.f, 0.f, 0.f};

  auto stage = [&](int buf, int k0) {
    #pragma unroll
    for (int r = 0; r < 2; ++r) {
      int kg = k0 + csrc[r];
      const __bf16* asrc;
      if (GATHER) asrc = (kg < K1) ? (a1row[r] + kg) : (a2row[r] + (kg - K1));
      else        asrc = a1row[r] + kg;
      GLOAD_LDS16(asrc, &sA[buf][wbase[r]]);
      GLOAD_LDS16(brow_[r] + kg, &sB[buf][wbase[r]]);
    }
  };

  stage(0, 0);
  __syncthreads();
  const int nk = KK >> 6;
  int cur = 0;
  for (int kt = 0; kt < nk; ++kt) {
    if (kt + 1 < nk) stage(cur ^ 1, (kt + 1) << 6);
    #pragma unroll
    for (int s = 0; s < 2; ++s) {
      bf16x8 a0 = *(const bf16x8*)&sA[cur][offA[0][s]];
      bf16x8 a1 = *(const bf16x8*)&sA[cur][offA[1][s]];
      bf16x8 b0 = *(const bf16x8*)&sB[cur][offB[0][s]];
      bf16x8 b1 = *(const bf16x8*)&sB[cur][offB[1][s]];
      acc[0][0] = __builtin_amdgcn_mfma_f32_16x16x32_bf16(a0, b0, acc[0][0], 0, 0, 0);
      acc[0][1] = __builtin_amdgcn_mfma_f32_16x16x32_bf16(a0, b1, acc[0][1], 0, 0, 0);
      acc[1][0] = __builtin_amdgcn_mfma_f32_16x16x32_bf16(a1, b0, acc[1][0], 0, 0, 0);
      acc[1][1] = __builtin_amdgcn_mfma_f32_16x16x32_bf16(a1, b1, acc[1][1], 0, 0, 0);
    }
    __syncthreads();
    cur ^= 1;
  }

  #pragma unroll
  for (int i = 0; i < 2; ++i)
    #pragma unroll
    for (int j = 0; j < 2; ++j)
      #pragma unroll
      for (int g = 0; g < 4; ++g) {
        int row = m0 + wr * 32 + i * 16 + (lane >> 4) * 4 + g;
        int col = n0 + wc * 32 + j * 16 + (lane & 15);
        if (row < M && col < N) {
          float v = acc[i][j][g];
          if (LEAKY) v = v > 0.f ? v : 0.1f * v;
          if (OUTF32) ((float*)Cout)[(size_t)row * N + col] = v;
          else        ((__bf16*)Cout)[(size_t)row * N + col] = (__bf16)v;
        }
      }
}

// ---------------- global max (clamped at 0 == reference's appended zero row) ----------------
__global__ __launch_bounds__(256) void gmax_kernel(const float* __restrict__ x, int n,
                                                   unsigned* __restrict__ gm) {
  float m = 0.f;
  for (size_t i = (size_t)blockIdx.x * blockDim.x + threadIdx.x; i < (size_t)n;
       i += (size_t)gridDim.x * blockDim.x)
    m = fmaxf(m, x[i]);
  #pragma unroll
  for (int s = 32; s >= 1; s >>= 1) m = fmaxf(m, __shfl_xor(m, s, 64));
  __shared__ float sm[4];
  if ((threadIdx.x & 63) == 0) sm[threadIdx.x >> 6] = m;
  __syncthreads();
  if (threadIdx.x == 0) {
    float mm = fmaxf(fmaxf(sm[0], sm[1]), fmaxf(sm[2], sm[3]));
    atomicMax(gm, __float_as_uint(mm));
  }
}

// ---------------- detection + fnorm; nnum==32 (neighbor row sums never exactly 0) ----------------
__global__ __launch_bounds__(256) void detect_kernel(
    const float* __restrict__ f6, const int* __restrict__ neigh,
    const float* __restrict__ gm_ptr, float* __restrict__ out_fnorm,
    float* __restrict__ out_scores, int N) {
  int n = blockIdx.x * 8 + (threadIdx.x >> 5);
  int c = threadIdx.x & 31;
  if (n >= N) return;
  float denom = gm_ptr[0] + 1e-6f;
  float fown = f6[(size_t)n * 32 + c];
  int idx_l = neigh[(size_t)n * 32 + c];
  float colsum = 0.f, colmax = -1e30f;
  for (int k = 0; k < 32; ++k) {
    int idx = __shfl(idx_l, k, 32);
    float v = f6[(size_t)idx * 32 + c];
    colsum += v;
    colmax = fmaxf(colmax, v);
  }
  float fs = fown / denom;
  float mean = (colsum / denom) * (1.f / 32.f);
  float x = fs - mean;
  float lms = fmaxf(x, 0.f) + log1pf(expf(-fabsf(x)));  // softplus
  float dm = fs;
  #pragma unroll
  for (int s = 16; s >= 1; s >>= 1) dm = fmaxf(dm, __shfl_xor(dm, s, 32));
  float as = lms * fs / (1e-6f + dm);
  float sc = as;
  #pragma unroll
  for (int s = 16; s >= 1; s >>= 1) sc = fmaxf(sc, __shfl_xor(sc, s, 32));
  float det = (fown == colmax) ? 1.f : 0.f;
  #pragma unroll
  for (int s = 16; s >= 1; s >>= 1) det = fmaxf(det, __shfl_xor(det, s, 32));
  float nn2 = fown * fown;
  #pragma unroll
  for (int s = 16; s >= 1; s >>= 1) nn2 += __shfl_xor(nn2, s, 32);
  float inv_nrm = 1.f / fmaxf(sqrtf(nn2), 1e-12f);
  out_fnorm[(size_t)n * 32 + c] = fown * inv_nrm;
  if (c == 0) out_scores[n] = sc * det;
}

extern "C" void kernel_launch(void* const* d_in, const int* in_sizes, int n_in,
                              void* d_out, int out_size, void* d_ws, size_t ws_size,
                              hipStream_t stream) {
  const float* features  = (const float*)d_in[0];
  const float* points0   = (const float*)d_in[1];
  const float* points1   = (const float*)d_in[2];
  const float* points2   = (const float*)d_in[3];
  const int* neighbors0  = (const int*)d_in[4];
  const int* neighbors1  = (const int*)d_in[5];
  const int* neighbors2  = (const int*)d_in[6];
  const int* pools0      = (const int*)d_in[7];
  const int* pools1      = (const int*)d_in[8];
  const int* upsamples0  = (const int*)d_in[9];
  const int* upsamples1  = (const int*)d_in[10];
  const float* kpoints   = (const float*)d_in[11];
  const float* W1  = (const float*)d_in[12];
  const float* W2  = (const float*)d_in[13];
  const float* W3  = (const float*)d_in[14];
  const float* W4  = (const float*)d_in[15];
  const float* W5  = (const float*)d_in[16];
  const float* Wu1 = (const float*)d_in[17];
  const float* Wu2 = (const float*)d_in[18];

  const float R0 = 0.5f;

  char* wp = (char*)d_ws;
  auto alloc = [&](size_t bytes) {
    char* r = wp;
    wp += (bytes + 255) & ~(size_t)255;
    return r;
  };
  __bf16* f0b  = (__bf16*)alloc((size_t)cN0 * 64 * 2);
  __bf16* f1b  = (__bf16*)alloc((size_t)cN1 * 64 * 2);
  __bf16* f2b  = (__bf16*)alloc((size_t)cN1 * 128 * 2);
  __bf16* f3b  = (__bf16*)alloc((size_t)cN2 * 128 * 2);
  __bf16* f4b  = (__bf16*)alloc((size_t)cN2 * 256 * 2);
  __bf16* f5b  = (__bf16*)alloc((size_t)cN1 * 128 * 2);
  float*  f6   = (float*)alloc((size_t)cN0 * 32 * 4);
  __bf16* WT2  = (__bf16*)alloc(960 * 64 * 2);
  __bf16* WT3  = (__bf16*)alloc(960 * 128 * 2);
  __bf16* WT4  = (__bf16*)alloc(1920 * 128 * 2);
  __bf16* WT5  = (__bf16*)alloc(1920 * 256 * 2);
  __bf16* WTu1 = (__bf16*)alloc(384 * 128 * 2);
  __bf16* WTu2 = (__bf16*)alloc(192 * 32 * 2);
  unsigned* gm = (unsigned*)alloc(256);
  __bf16* fkb  = (__bf16*)alloc((size_t)cN1 * 960 * 2);

  convert_wt<<<dim3(1920, 6), 256, 0, stream>>>(W2, W3, W4, W5, Wu1, Wu2,
                                                WT2, WT3, WT4, WT5, WTu1, WTu2);
  kpconv_l1<<<cN0 / 4, 256, 0, stream>>>(points0, neighbors0, features, kpoints, W1, f0b, R0);

  // L2: strided, f0 -> f1 [N1,64]
  kpconv_agg<64><<<cN1 / 2, 256, 0, stream>>>(points1, points0, pools0, f0b, kpoints, fkb, cN1, R0);
  gemm_mfma<true, false, false><<<dim3(1, 235), 256, 0, stream>>>(
      fkb, nullptr, nullptr, 0, WT2, f1b, cN1, 64, 960);
  // L3: simple, f1 -> f2 [N1,128]
  kpconv_agg<64><<<cN1 / 2, 256, 0, stream>>>(points1, points1, neighbors1, f1b, kpoints, fkb, cN1, 2.f * R0);
  gemm_mfma<true, false, false><<<dim3(2, 235), 256, 0, stream>>>(
      fkb, nullptr, nullptr, 0, WT3, f2b, cN1, 128, 960);
  // L4: strided, f2 -> f3 [N2,128]
  kpconv_agg<128><<<cN2 / 2, 256, 0, stream>>>(points2, points1, pools1, f2b, kpoints, fkb, cN2, 2.f * R0);
  gemm_mfma<true, false, false><<<dim3(2, 59), 256, 0, stream>>>(
      fkb, nullptr, nullptr, 0, WT4, f3b, cN2, 128, 1920);
  // L5: simple, f3 -> f4 [N2,256]
  kpconv_agg<128><<<cN2 / 2, 256, 0, stream>>>(points2, points2, neighbors2, f3b, kpoints, fkb, cN2, 4.f * R0);
  gemm_mfma<true, false, false><<<dim3(4, 59), 256, 0, stream>>>(
      fkb, nullptr, nullptr, 0, WT5, f4b, cN2, 256, 1920);
  // D1: f5 = leaky(concat(f4[up1], f2) @ Wu1)
  gemm_mfma<true, true, false><<<dim3(2, 235), 256, 0, stream>>>(
      f4b, f2b, upsamples1, 256, WTu1, f5b, cN1, 128, 384);
  // D2: f6 = concat(f5[up0], f0) @ Wu2  (f32 out)
  gemm_mfma<false, true, true><<<dim3(1, 938), 256, 0, stream>>>(
      f5b, f0b, upsamples0, 128, WTu2, f6, cN0, 32, 192);

  hipMemsetAsync(gm, 0, 4, stream);
  gmax_kernel<<<1024, 256, 0, stream>>>(f6, cN0 * 32, gm);
  float* out_fnorm = (float*)d_out;
  float* out_scores = out_fnorm + (size_t)cN0 * 32;
  detect_kernel<<<(cN0 + 7) / 8, 256, 0, stream>>>(f6, neighbors0, (const float*)gm,
                                                   out_fnorm, out_scores, cN0);
}

// Round 3
// 269.523 us; speedup vs baseline: 3.3213x; 1.2120x over previous
//
#include <hip/hip_runtime.h>
#include <math.h>

static const int cN0 = 60000;
static const int cN1 = 15000;
static const int cN2 = 3750;

typedef __bf16 bf16x8 __attribute__((ext_vector_type(8)));
typedef float f32x4 __attribute__((ext_vector_type(4)));

#define GLOAD_LDS16(gsrc, ldst)                                                        \
  __builtin_amdgcn_global_load_lds((const __attribute__((address_space(1))) void*)(gsrc), \
                                   (__attribute__((address_space(3))) void*)(ldst), 16, 0, 0)

// ---------------- weight convert + transpose: WT[N][K] bf16 from W[K][N] f32 ----------------
__global__ __launch_bounds__(256) void convert_wt(
    const float* __restrict__ W2, const float* __restrict__ W3, const float* __restrict__ W4,
    const float* __restrict__ W5, const float* __restrict__ Wu1, const float* __restrict__ Wu2,
    __bf16* __restrict__ T2, __bf16* __restrict__ T3, __bf16* __restrict__ T4,
    __bf16* __restrict__ T5, __bf16* __restrict__ Tu1, __bf16* __restrict__ Tu2) {
  int which = blockIdx.y;
  const float* src;
  __bf16* dst;
  int Kd, Nd;
  switch (which) {
    case 0: src = W2;  dst = T2;  Kd = 960;  Nd = 64;  break;
    case 1: src = W3;  dst = T3;  Kd = 960;  Nd = 128; break;
    case 2: src = W4;  dst = T4;  Kd = 1920; Nd = 128; break;
    case 3: src = W5;  dst = T5;  Kd = 1920; Nd = 256; break;
    case 4: src = Wu1; dst = Tu1; Kd = 384;  Nd = 128; break;
    default: src = Wu2; dst = Tu2; Kd = 192; Nd = 32;  break;
  }
  int total = Kd * Nd;
  for (int e = blockIdx.x * 256 + threadIdx.x; e < total; e += gridDim.x * 256) {
    int n = e / Kd, k = e % Kd;
    dst[e] = (__bf16)src[(size_t)k * Nd + n];
  }
}

// ---------------- L1 kpconv: Cin=1 -> 64, 16 points/block, 4 points/wave ----------------
__global__ __launch_bounds__(256) void kpconv_l1(
    const float* __restrict__ pts, const int* __restrict__ neigh,
    const float* __restrict__ feat, const float* __restrict__ kpts,
    const float* __restrict__ W1, __bf16* __restrict__ f0, float extent) {
  const int t = threadIdx.x;
  const int n0b = blockIdx.x * 16;
  __shared__ float s_nb[32][16][4];   // [k][pt][xyzf]
  __shared__ float s_fk[16][16];      // [pt][p]
  // load phase: 512 gathered records, 2 per thread
  #pragma unroll
  for (int i = 0; i < 2; ++i) {
    int e = t + i * 256;
    int pt = e & 15, k = e >> 4;
    int idx = neigh[(size_t)(n0b + pt) * 32 + k];
    f32x4 rec;
    rec[0] = pts[(size_t)idx * 3 + 0];
    rec[1] = pts[(size_t)idx * 3 + 1];
    rec[2] = pts[(size_t)idx * 3 + 2];
    rec[3] = feat[idx];
    *(f32x4*)&s_nb[k][pt][0] = rec;
  }
  __syncthreads();
  // dist/influence phase: lane = 16*g + p; group g handles point pt = wave*4+g
  const int lane = t & 63, wave = t >> 6;
  const int g = lane >> 4, p_raw = lane & 15;
  const int p = p_raw < 15 ? p_raw : 0;
  const int pt = wave * 4 + g;
  const int n = n0b + pt;
  const float inv = 1.f / extent;
  const float kx = pts[(size_t)n * 3 + 0] + kpts[p * 3 + 0] * extent;
  const float ky = pts[(size_t)n * 3 + 1] + kpts[p * 3 + 1] * extent;
  const float kz = pts[(size_t)n * 3 + 2] + kpts[p * 3 + 2] * extent;
  float fk = 0.f;
  #pragma unroll 8
  for (int k = 0; k < 32; ++k) {
    f32x4 rec = *(const f32x4*)&s_nb[k][pt][0];
    float dx = rec[0] - kx, dy = rec[1] - ky, dz = rec[2] - kz;
    float d = sqrtf(dx * dx + dy * dy + dz * dz);
    fk += fmaxf(0.f, 1.f - d * inv) * rec[3];
  }
  if (p_raw < 15) s_fk[pt][p_raw] = fk;
  __syncthreads();
  // output phase: 16 pts x 64 ch = 1024 outputs, 4 per thread
  #pragma unroll
  for (int o = 0; o < 4; ++o) {
    int e = o * 256 + t;
    int opt = e >> 6, c = e & 63;
    float acc = 0.f;
    #pragma unroll
    for (int pp = 0; pp < 15; ++pp) acc += s_fk[opt][pp] * W1[pp * 64 + c];
    acc = acc > 0.f ? acc : 0.1f * acc;
    f0[(size_t)(n0b + opt) * 64 + c] = (__bf16)acc;
  }
}

// ---------------- neighbor aggregation: fkb[n, p*CIN+c] bf16, 2 points/block ----------------
template <int CIN>
__global__ __launch_bounds__(256) void kpconv_agg(
    const float* __restrict__ qpts, const float* __restrict__ spts,
    const int* __restrict__ neigh, const __bf16* __restrict__ F,
    const float* __restrict__ kpts, __bf16* __restrict__ fkb,
    int M, float extent) {
  constexpr int CPR = CIN / 8;  // 16B chunks per F row
  const int pt = threadIdx.x >> 7;
  const int st = threadIdx.x & 127;
  const int n = blockIdx.x * 2 + pt;
  __shared__ int s_idx[2][32];
  __shared__ float s_infl[2][32][16];
  __shared__ __bf16 s_F[2][32][CIN];
  float inv = 1.f / extent;
  float qx = qpts[(size_t)n * 3 + 0], qy = qpts[(size_t)n * 3 + 1], qz = qpts[(size_t)n * 3 + 2];
  if (st < 32) {
    int idx = neigh[(size_t)n * 32 + st];
    s_idx[pt][st] = idx;
    float sx = spts[(size_t)idx * 3 + 0] - qx;
    float sy = spts[(size_t)idx * 3 + 1] - qy;
    float sz = spts[(size_t)idx * 3 + 2] - qz;
    #pragma unroll
    for (int p = 0; p < 15; ++p) {
      float dx = sx - kpts[p * 3 + 0] * extent;
      float dy = sy - kpts[p * 3 + 1] * extent;
      float dz = sz - kpts[p * 3 + 2] * extent;
      float d = sqrtf(dx * dx + dy * dy + dz * dz);
      s_infl[pt][st][p] = fmaxf(0.f, 1.f - d * inv);
    }
  }
  __syncthreads();
  #pragma unroll
  for (int ch = st; ch < 32 * CPR; ch += 128) {
    int k = ch / CPR, c8 = ch % CPR;
    *(bf16x8*)&s_F[pt][k][c8 * 8] = *(const bf16x8*)(F + (size_t)s_idx[pt][k] * CIN + c8 * 8);
  }
  __syncthreads();
  int p = st >> 3, cb = st & 7;
  if (p < 15) {
    constexpr int CW = CIN / 8;  // cols per thread
    const int c0 = cb * CW;
    float acc[CW];
    #pragma unroll
    for (int j = 0; j < CW; ++j) acc[j] = 0.f;
    #pragma unroll 4
    for (int k = 0; k < 32; ++k) {
      float w = s_infl[pt][k][p];
      #pragma unroll
      for (int v = 0; v < CW / 8; ++v) {
        bf16x8 fv = *(const bf16x8*)&s_F[pt][k][c0 + v * 8];
        #pragma unroll
        for (int j = 0; j < 8; ++j) acc[v * 8 + j] += w * (float)fv[j];
      }
    }
    size_t obase = (size_t)n * (15 * CIN) + p * CIN + c0;
    #pragma unroll
    for (int v = 0; v < CW / 8; ++v) {
      bf16x8 ov;
      #pragma unroll
      for (int j = 0; j < 8; ++j) ov[j] = (__bf16)acc[v * 8 + j];
      *(bf16x8*)&fkb[obase + v * 8] = ov;
    }
  }
}

// ---------------- MFMA bf16 GEMM: C[M,N] = Aeff[M,KK] * BT[N,KK]^T ----------------
// GATHER: Aeff row m = concat(A1[gidx[m]][0:K1], A2[m][0:KK-K1]). BK=64, tile 64x64.
template <bool LEAKY, bool GATHER, bool OUTF32>
__global__ __launch_bounds__(256, 2) void gemm_mfma(
    const __bf16* __restrict__ A1, const __bf16* __restrict__ A2,
    const int* __restrict__ gidx, const int K1,
    const __bf16* __restrict__ BT, void* __restrict__ Cout,
    const int M, const int N, const int KK) {
  __shared__ __bf16 sA[2][4096];
  __shared__ __bf16 sB[2][4096];
  const int t = threadIdx.x;
  const int lane = t & 63, wave = t >> 6;
  const int wr = wave >> 1, wc = wave & 1;
  const int m0 = blockIdx.y * 64, n0 = blockIdx.x * 64;
  const int K2 = KK - K1;

  const __bf16* a1row[2];
  const __bf16* a2row[2];
  const __bf16* brow_[2];
  int csrc[2], wbase[2];
  #pragma unroll
  for (int r = 0; r < 2; ++r) {
    int slot = r * 256 + wave * 64 + lane;
    int row = slot >> 3;
    csrc[r] = ((slot & 7) ^ (row & 7)) * 8;
    wbase[r] = (r * 256 + wave * 64) * 8;
    int gm = m0 + row; if (gm > M - 1) gm = M - 1;
    if (GATHER) {
      a1row[r] = A1 + (size_t)gidx[gm] * K1;
      a2row[r] = A2 + (size_t)gm * (size_t)K2;
    } else {
      a1row[r] = A1 + (size_t)gm * (size_t)KK;
    }
    int gn = n0 + row; if (gn > N - 1) gn = N - 1;
    brow_[r] = BT + (size_t)gn * (size_t)KK;
  }

  int offA[2][2], offB[2][2];
  #pragma unroll
  for (int i = 0; i < 2; ++i)
    #pragma unroll
    for (int s = 0; s < 2; ++s) {
      int ra = wr * 32 + i * 16 + (lane & 15);
      int rb = wc * 32 + i * 16 + (lane & 15);
      int ch = s * 4 + (lane >> 4);
      offA[i][s] = ra * 64 + (ch ^ (ra & 7)) * 8;
      offB[i][s] = rb * 64 + (ch ^ (rb & 7)) * 8;
    }

  f32x4 acc[2][2];
  #pragma unroll
  for (int i = 0; i < 2; ++i)
    #pragma unroll
    for (int j = 0; j < 2; ++j) acc[i][j] = (f32x4){0.f, 0.f, 0.f, 0.f};

  auto stage = [&](int buf, int k0) {
    #pragma unroll
    for (int r = 0; r < 2; ++r) {
      int kg = k0 + csrc[r];
      const __bf16* asrc;
      if (GATHER) asrc = (kg < K1) ? (a1row[r] + kg) : (a2row[r] + (kg - K1));
      else        asrc = a1row[r] + kg;
      GLOAD_LDS16(asrc, &sA[buf][wbase[r]]);
      GLOAD_LDS16(brow_[r] + kg, &sB[buf][wbase[r]]);
    }
  };

  stage(0, 0);
  __syncthreads();
  const int nk = KK >> 6;
  int cur = 0;
  for (int kt = 0; kt < nk; ++kt) {
    if (kt + 1 < nk) stage(cur ^ 1, (kt + 1) << 6);
    #pragma unroll
    for (int s = 0; s < 2; ++s) {
      bf16x8 a0 = *(const bf16x8*)&sA[cur][offA[0][s]];
      bf16x8 a1 = *(const bf16x8*)&sA[cur][offA[1][s]];
      bf16x8 b0 = *(const bf16x8*)&sB[cur][offB[0][s]];
      bf16x8 b1 = *(const bf16x8*)&sB[cur][offB[1][s]];
      acc[0][0] = __builtin_amdgcn_mfma_f32_16x16x32_bf16(a0, b0, acc[0][0], 0, 0, 0);
      acc[0][1] = __builtin_amdgcn_mfma_f32_16x16x32_bf16(a0, b1, acc[0][1], 0, 0, 0);
      acc[1][0] = __builtin_amdgcn_mfma_f32_16x16x32_bf16(a1, b0, acc[1][0], 0, 0, 0);
      acc[1][1] = __builtin_amdgcn_mfma_f32_16x16x32_bf16(a1, b1, acc[1][1], 0, 0, 0);
    }
    __syncthreads();
    cur ^= 1;
  }

  #pragma unroll
  for (int i = 0; i < 2; ++i)
    #pragma unroll
    for (int j = 0; j < 2; ++j)
      #pragma unroll
      for (int g = 0; g < 4; ++g) {
        int row = m0 + wr * 32 + i * 16 + (lane >> 4) * 4 + g;
        int col = n0 + wc * 32 + j * 16 + (lane & 15);
        if (row < M && col < N) {
          float v = acc[i][j][g];
          if (LEAKY) v = v > 0.f ? v : 0.1f * v;
          if (OUTF32) ((float*)Cout)[(size_t)row * N + col] = v;
          else        ((__bf16*)Cout)[(size_t)row * N + col] = (__bf16)v;
        }
      }
}

// ---------------- global max (clamped at 0 == reference's appended zero row) ----------------
__global__ __launch_bounds__(256) void gmax_kernel(const float* __restrict__ x, int n,
                                                   unsigned* __restrict__ gm) {
  float m = 0.f;
  for (size_t i = (size_t)blockIdx.x * blockDim.x + threadIdx.x; i < (size_t)n;
       i += (size_t)gridDim.x * blockDim.x)
    m = fmaxf(m, x[i]);
  #pragma unroll
  for (int s = 32; s >= 1; s >>= 1) m = fmaxf(m, __shfl_xor(m, s, 64));
  __shared__ float sm[4];
  if ((threadIdx.x & 63) == 0) sm[threadIdx.x >> 6] = m;
  __syncthreads();
  if (threadIdx.x == 0) {
    float mm = fmaxf(fmaxf(sm[0], sm[1]), fmaxf(sm[2], sm[3]));
    atomicMax(gm, __float_as_uint(mm));
  }
}

// ---------------- detection + fnorm; nnum==32 (neighbor row sums never exactly 0) ----------------
__global__ __launch_bounds__(256) void detect_kernel(
    const float* __restrict__ f6, const int* __restrict__ neigh,
    const float* __restrict__ gm_ptr, float* __restrict__ out_fnorm,
    float* __restrict__ out_scores, int N) {
  int n = blockIdx.x * 8 + (threadIdx.x >> 5);
  int c = threadIdx.x & 31;
  if (n >= N) return;
  float denom = gm_ptr[0] + 1e-6f;
  float fown = f6[(size_t)n * 32 + c];
  int idx_l = neigh[(size_t)n * 32 + c];
  float colsum = 0.f, colmax = -1e30f;
  for (int k = 0; k < 32; ++k) {
    int idx = __shfl(idx_l, k, 32);
    float v = f6[(size_t)idx * 32 + c];
    colsum += v;
    colmax = fmaxf(colmax, v);
  }
  float fs = fown / denom;
  float mean = (colsum / denom) * (1.f / 32.f);
  float x = fs - mean;
  float lms = fmaxf(x, 0.f) + log1pf(expf(-fabsf(x)));  // softplus
  float dm = fs;
  #pragma unroll
  for (int s = 16; s >= 1; s >>= 1) dm = fmaxf(dm, __shfl_xor(dm, s, 32));
  float as = lms * fs / (1e-6f + dm);
  float sc = as;
  #pragma unroll
  for (int s = 16; s >= 1; s >>= 1) sc = fmaxf(sc, __shfl_xor(sc, s, 32));
  float det = (fown == colmax) ? 1.f : 0.f;
  #pragma unroll
  for (int s = 16; s >= 1; s >>= 1) det = fmaxf(det, __shfl_xor(det, s, 32));
  float nn2 = fown * fown;
  #pragma unroll
  for (int s = 16; s >= 1; s >>= 1) nn2 += __shfl_xor(nn2, s, 32);
  float inv_nrm = 1.f / fmaxf(sqrtf(nn2), 1e-12f);
  out_fnorm[(size_t)n * 32 + c] = fown * inv_nrm;
  if (c == 0) out_scores[n] = sc * det;
}

extern "C" void kernel_launch(void* const* d_in, const int* in_sizes, int n_in,
                              void* d_out, int out_size, void* d_ws, size_t ws_size,
                              hipStream_t stream) {
  const float* features  = (const float*)d_in[0];
  const float* points0   = (const float*)d_in[1];
  const float* points1   = (const float*)d_in[2];
  const float* points2   = (const float*)d_in[3];
  const int* neighbors0  = (const int*)d_in[4];
  const int* neighbors1  = (const int*)d_in[5];
  const int* neighbors2  = (const int*)d_in[6];
  const int* pools0      = (const int*)d_in[7];
  const int* pools1      = (const int*)d_in[8];
  const int* upsamples0  = (const int*)d_in[9];
  const int* upsamples1  = (const int*)d_in[10];
  const float* kpoints   = (const float*)d_in[11];
  const float* W1  = (const float*)d_in[12];
  const float* W2  = (const float*)d_in[13];
  const float* W3  = (const float*)d_in[14];
  const float* W4  = (const float*)d_in[15];
  const float* W5  = (const float*)d_in[16];
  const float* Wu1 = (const float*)d_in[17];
  const float* Wu2 = (const float*)d_in[18];

  const float R0 = 0.5f;

  char* wp = (char*)d_ws;
  auto alloc = [&](size_t bytes) {
    char* r = wp;
    wp += (bytes + 255) & ~(size_t)255;
    return r;
  };
  __bf16* f0b  = (__bf16*)alloc((size_t)cN0 * 64 * 2);
  __bf16* f1b  = (__bf16*)alloc((size_t)cN1 * 64 * 2);
  __bf16* f2b  = (__bf16*)alloc((size_t)cN1 * 128 * 2);
  __bf16* f3b  = (__bf16*)alloc((size_t)cN2 * 128 * 2);
  __bf16* f4b  = (__bf16*)alloc((size_t)cN2 * 256 * 2);
  __bf16* f5b  = (__bf16*)alloc((size_t)cN1 * 128 * 2);
  float*  f6   = (float*)alloc((size_t)cN0 * 32 * 4);
  __bf16* WT2  = (__bf16*)alloc(960 * 64 * 2);
  __bf16* WT3  = (__bf16*)alloc(960 * 128 * 2);
  __bf16* WT4  = (__bf16*)alloc(1920 * 128 * 2);
  __bf16* WT5  = (__bf16*)alloc(1920 * 256 * 2);
  __bf16* WTu1 = (__bf16*)alloc(384 * 128 * 2);
  __bf16* WTu2 = (__bf16*)alloc(192 * 32 * 2);
  unsigned* gm = (unsigned*)alloc(256);
  __bf16* fkb  = (__bf16*)alloc((size_t)cN1 * 960 * 2);

  convert_wt<<<dim3(1920, 6), 256, 0, stream>>>(W2, W3, W4, W5, Wu1, Wu2,
                                                WT2, WT3, WT4, WT5, WTu1, WTu2);
  kpconv_l1<<<cN0 / 16, 256, 0, stream>>>(points0, neighbors0, features, kpoints, W1, f0b, R0);

  // L2: strided, f0 -> f1 [N1,64]
  kpconv_agg<64><<<cN1 / 2, 256, 0, stream>>>(points1, points0, pools0, f0b, kpoints, fkb, cN1, R0);
  gemm_mfma<true, false, false><<<dim3(1, 235), 256, 0, stream>>>(
      fkb, nullptr, nullptr, 0, WT2, f1b, cN1, 64, 960);
  // L3: simple, f1 -> f2 [N1,128]
  kpconv_agg<64><<<cN1 / 2, 256, 0, stream>>>(points1, points1, neighbors1, f1b, kpoints, fkb, cN1, 2.f * R0);
  gemm_mfma<true, false, false><<<dim3(2, 235), 256, 0, stream>>>(
      fkb, nullptr, nullptr, 0, WT3, f2b, cN1, 128, 960);
  // L4: strided, f2 -> f3 [N2,128]
  kpconv_agg<128><<<cN2 / 2, 256, 0, stream>>>(points2, points1, pools1, f2b, kpoints, fkb, cN2, 2.f * R0);
  gemm_mfma<true, false, false><<<dim3(2, 59), 256, 0, stream>>>(
      fkb, nullptr, nullptr, 0, WT4, f3b, cN2, 128, 1920);
  // L5: simple, f3 -> f4 [N2,256]
  kpconv_agg<128><<<cN2 / 2, 256, 0, stream>>>(points2, points2, neighbors2, f3b, kpoints, fkb, cN2, 4.f * R0);
  gemm_mfma<true, false, false><<<dim3(4, 59), 256, 0, stream>>>(
      fkb, nullptr, nullptr, 0, WT5, f4b, cN2, 256, 1920);
  // D1: f5 = leaky(concat(f4[up1], f2) @ Wu1)
  gemm_mfma<true, true, false><<<dim3(2, 235), 256, 0, stream>>>(
      f4b, f2b, upsamples1, 256, WTu1, f5b, cN1, 128, 384);
  // D2: f6 = concat(f5[up0], f0) @ Wu2  (f32 out)
  gemm_mfma<false, true, true><<<dim3(1, 938), 256, 0, stream>>>(
      f5b, f0b, upsamples0, 128, WTu2, f6, cN0, 32, 192);

  hipMemsetAsync(gm, 0, 4, stream);
  gmax_kernel<<<1024, 256, 0, stream>>>(f6, cN0 * 32, gm);
  float* out_fnorm = (float*)d_out;
  float* out_scores = out_fnorm + (size_t)cN0 * 32;
  detect_kernel<<<(cN0 + 7) / 8, 256, 0, stream>>>(f6, neighbors0, (const float*)gm,
                                                   out_fnorm, out_scores, cN0);
}

// Round 4
// 224.644 us; speedup vs baseline: 3.9848x; 1.1998x over previous
//
#include <hip/hip_runtime.h>
#include <math.h>

static const int cN0 = 60000;
static const int cN1 = 15000;
static const int cN2 = 3750;

typedef __bf16 bf16x8 __attribute__((ext_vector_type(8)));
typedef float f32x4 __attribute__((ext_vector_type(4)));

#define GLOAD_LDS16(gsrc, ldst)                                                        \
  __builtin_amdgcn_global_load_lds((const __attribute__((address_space(1))) void*)(gsrc), \
                                   (__attribute__((address_space(3))) void*)(ldst), 16, 0, 0)

// ---------------- prep: pack points(+feat) into float4; transpose weights to bf16 ----------------
__global__ __launch_bounds__(256) void prep_kernel(
    const float* __restrict__ pts0, const float* __restrict__ feat,
    const float* __restrict__ pts1, const float* __restrict__ pts2,
    const float* __restrict__ W2, const float* __restrict__ W3, const float* __restrict__ W4,
    const float* __restrict__ W5, const float* __restrict__ Wu1, const float* __restrict__ Wu2,
    float4* __restrict__ pk0, float4* __restrict__ pk1, float4* __restrict__ pk2,
    __bf16* __restrict__ T2, __bf16* __restrict__ T3, __bf16* __restrict__ T4,
    __bf16* __restrict__ T5, __bf16* __restrict__ Tu1, __bf16* __restrict__ Tu2) {
  int role = blockIdx.y;
  int tid = blockIdx.x * 256 + threadIdx.x;
  int stride = gridDim.x * 256;
  if (role < 3) {
    const float* p = role == 0 ? pts0 : (role == 1 ? pts1 : pts2);
    float4* o = role == 0 ? pk0 : (role == 1 ? pk1 : pk2);
    int n = role == 0 ? cN0 : (role == 1 ? cN1 : cN2);
    for (int i = tid; i < n; i += stride) {
      float4 v;
      v.x = p[(size_t)i * 3 + 0];
      v.y = p[(size_t)i * 3 + 1];
      v.z = p[(size_t)i * 3 + 2];
      v.w = role == 0 ? feat[i] : 0.f;
      o[i] = v;
    }
  } else {
    const float* src;
    __bf16* dst;
    int Kd, Nd;
    switch (role) {
      case 3: src = W2;  dst = T2;  Kd = 960;  Nd = 64;  break;
      case 4: src = W3;  dst = T3;  Kd = 960;  Nd = 128; break;
      case 5: src = W4;  dst = T4;  Kd = 1920; Nd = 128; break;
      case 6: src = W5;  dst = T5;  Kd = 1920; Nd = 256; break;
      case 7: src = Wu1; dst = Tu1; Kd = 384;  Nd = 128; break;
      default: src = Wu2; dst = Tu2; Kd = 192; Nd = 32;  break;
    }
    int total = Kd * Nd;
    for (int e = tid; e < total; e += stride) {
      int n = e / Kd, k = e % Kd;
      dst[e] = (__bf16)src[(size_t)k * Nd + n];
    }
  }
}

// ---------------- L1 kpconv: Cin=1 -> 64, 16 points/block, packed float4 gather ----------------
__global__ __launch_bounds__(256) void kpconv_l1(
    const float4* __restrict__ pk, const int* __restrict__ neigh,
    const float* __restrict__ kpts, const float* __restrict__ W1,
    __bf16* __restrict__ f0, float extent) {
  const int t = threadIdx.x;
  const int n0b = blockIdx.x * 16;
  __shared__ float s_nb[32][16][4];   // [k][pt][xyzf]
  __shared__ float s_fk[16][16];      // [pt][p]
  __shared__ float s_W[960];
  for (int i = t; i < 960; i += 256) s_W[i] = W1[i];
  #pragma unroll
  for (int i = 0; i < 2; ++i) {
    int e = t + i * 256;
    int pt = e & 15, k = e >> 4;
    int idx = neigh[(size_t)(n0b + pt) * 32 + k];
    *(float4*)&s_nb[k][pt][0] = pk[idx];
  }
  __syncthreads();
  const int lane = t & 63, wave = t >> 6;
  const int g = lane >> 4, p_raw = lane & 15;
  const int p = p_raw < 15 ? p_raw : 0;
  const int pt = wave * 4 + g;
  const int n = n0b + pt;
  const float inv = 1.f / extent;
  float4 q = pk[n];
  const float kx = q.x + kpts[p * 3 + 0] * extent;
  const float ky = q.y + kpts[p * 3 + 1] * extent;
  const float kz = q.z + kpts[p * 3 + 2] * extent;
  float fk = 0.f;
  #pragma unroll 8
  for (int k = 0; k < 32; ++k) {
    f32x4 rec = *(const f32x4*)&s_nb[k][pt][0];
    float dx = rec[0] - kx, dy = rec[1] - ky, dz = rec[2] - kz;
    float d = sqrtf(dx * dx + dy * dy + dz * dz);
    fk += fmaxf(0.f, 1.f - d * inv) * rec[3];
  }
  if (p_raw < 15) s_fk[pt][p_raw] = fk;
  __syncthreads();
  #pragma unroll
  for (int o = 0; o < 4; ++o) {
    int e = o * 256 + t;
    int opt = e >> 6, c = e & 63;
    float acc = 0.f;
    #pragma unroll
    for (int pp = 0; pp < 15; ++pp) acc += s_fk[opt][pp] * s_W[pp * 64 + c];
    acc = acc > 0.f ? acc : 0.1f * acc;
    f0[(size_t)(n0b + opt) * 64 + c] = (__bf16)acc;
  }
}

// ---------------- MFMA neighbor aggregation: fkb[n][p*CIN+c] = sum_k infl[k,p]*F[idx,c] ----------
// One 16x16x32 MFMA per (point, 16-col chunk): A=infl[16p x 32k], B=F[32k x 16c].
template <int CIN, int PTS>
__global__ __launch_bounds__(256) void kpconv_agg_mfma(
    const float4* __restrict__ qp, const float4* __restrict__ sp,
    const int* __restrict__ neigh, const __bf16* __restrict__ F,
    const float* __restrict__ kpts, __bf16* __restrict__ fkb,
    int M, float extent) {
  constexpr int ROWS = PTS * 32;        // gathered rows per block
  constexpr int TPR = 256 / ROWS;       // threads per row (1 or 2)
  constexpr int CPT = CIN / (8 * TPR);  // bf16x8 chunks per thread
  constexpr int NCC = CIN / 16;         // MFMA col chunks per point
  constexpr int PPW = PTS / 4;          // points per wave
  __shared__ __bf16 s_F[PTS][32][CIN];
  __shared__ __bf16 s_infl[PTS][16][40];  // padded stride 40 (80B): A-frag reads conflict-free
  const int t = threadIdx.x;
  const int rowid = t / TPR, half = t % TPR;
  const int pt = rowid >> 5, k = rowid & 31;
  const int n = blockIdx.x * PTS + pt;
  const int n_eff = n < M ? n : M - 1;
  const int idx = neigh[(size_t)n_eff * 32 + k];
  {  // gather F row (vectorized)
    const __bf16* src = F + (size_t)idx * CIN + half * (CIN / TPR);
    __bf16* dst = &s_F[pt][k][half * (CIN / TPR)];
    #pragma unroll
    for (int j = 0; j < CPT; ++j) *(bf16x8*)(dst + j * 8) = *(const bf16x8*)(src + j * 8);
  }
  {  // influence for this (pt, k) across all 15 kernel points
    float4 q = qp[n_eff];
    float4 s = sp[idx];
    float sx = s.x - q.x, sy = s.y - q.y, sz = s.z - q.z;
    float inv = 1.f / extent;
    #pragma unroll
    for (int p = 0; p < 15; ++p) {
      float dx = sx - kpts[p * 3 + 0] * extent;
      float dy = sy - kpts[p * 3 + 1] * extent;
      float dz = sz - kpts[p * 3 + 2] * extent;
      float d = sqrtf(dx * dx + dy * dy + dz * dz);
      s_infl[pt][p][k] = (__bf16)fmaxf(0.f, 1.f - d * inv);
    }
  }
  __syncthreads();
  const int lane = t & 63, wave = t >> 6;
  const int g = lane >> 4, c16 = lane & 15;
  #pragma unroll
  for (int qq = 0; qq < PPW; ++qq) {
    const int lpt = wave * PPW + qq;
    const int nn = blockIdx.x * PTS + lpt;
    bf16x8 a = *(const bf16x8*)&s_infl[lpt][c16][g * 8];  // A row p=c16, k=g*8..g*8+7
    if (nn < M) {
      const size_t base = (size_t)nn * (15 * CIN);
      #pragma unroll
      for (int cc = 0; cc < NCC; ++cc) {
        bf16x8 b;
        #pragma unroll
        for (int j = 0; j < 8; ++j) b[j] = s_F[lpt][g * 8 + j][cc * 16 + c16];
        f32x4 acc = __builtin_amdgcn_mfma_f32_16x16x32_bf16(a, b, (f32x4){0.f, 0.f, 0.f, 0.f}, 0, 0, 0);
        #pragma unroll
        for (int r = 0; r < 4; ++r) {
          int p = g * 4 + r;
          if (p < 15) fkb[base + (size_t)p * CIN + cc * 16 + c16] = (__bf16)acc[r];
        }
      }
    }
  }
}

// ---------------- MFMA bf16 GEMM: C[M,N] = Aeff[M,KK] * BT[N,KK]^T ----------------
template <bool LEAKY, bool GATHER, bool OUTF32, bool MAXOUT>
__global__ __launch_bounds__(256, 2) void gemm_mfma(
    const __bf16* __restrict__ A1, const __bf16* __restrict__ A2,
    const int* __restrict__ gidx, const int K1,
    const __bf16* __restrict__ BT, void* __restrict__ Cout,
    const int M, const int N, const int KK, unsigned* __restrict__ gmax) {
  __shared__ __bf16 sA[2][4096];
  __shared__ __bf16 sB[2][4096];
  __shared__ float s_max[4];
  const int t = threadIdx.x;
  const int lane = t & 63, wave = t >> 6;
  const int wr = wave >> 1, wc = wave & 1;
  const int m0 = blockIdx.y * 64, n0 = blockIdx.x * 64;
  const int K2 = KK - K1;

  const __bf16* a1row[2];
  const __bf16* a2row[2];
  const __bf16* brow_[2];
  int csrc[2], wbase[2];
  #pragma unroll
  for (int r = 0; r < 2; ++r) {
    int slot = r * 256 + wave * 64 + lane;
    int row = slot >> 3;
    csrc[r] = ((slot & 7) ^ (row & 7)) * 8;
    wbase[r] = (r * 256 + wave * 64) * 8;
    int gm = m0 + row; if (gm > M - 1) gm = M - 1;
    if (GATHER) {
      a1row[r] = A1 + (size_t)gidx[gm] * K1;
      a2row[r] = A2 + (size_t)gm * (size_t)K2;
    } else {
      a1row[r] = A1 + (size_t)gm * (size_t)KK;
    }
    int gn = n0 + row; if (gn > N - 1) gn = N - 1;
    brow_[r] = BT + (size_t)gn * (size_t)KK;
  }

  int offA[2][2], offB[2][2];
  #pragma unroll
  for (int i = 0; i < 2; ++i)
    #pragma unroll
    for (int s = 0; s < 2; ++s) {
      int ra = wr * 32 + i * 16 + (lane & 15);
      int rb = wc * 32 + i * 16 + (lane & 15);
      int ch = s * 4 + (lane >> 4);
      offA[i][s] = ra * 64 + (ch ^ (ra & 7)) * 8;
      offB[i][s] = rb * 64 + (ch ^ (rb & 7)) * 8;
    }

  f32x4 acc[2][2];
  #pragma unroll
  for (int i = 0; i < 2; ++i)
    #pragma unroll
    for (int j = 0; j < 2; ++j) acc[i][j] = (f32x4){0.f, 0.f, 0.f, 0.f};

  auto stage = [&](int buf, int k0) {
    #pragma unroll
    for (int r = 0; r < 2; ++r) {
      int kg = k0 + csrc[r];
      const __bf16* asrc;
      if (GATHER) asrc = (kg < K1) ? (a1row[r] + kg) : (a2row[r] + (kg - K1));
      else        asrc = a1row[r] + kg;
      GLOAD_LDS16(asrc, &sA[buf][wbase[r]]);
      GLOAD_LDS16(brow_[r] + kg, &sB[buf][wbase[r]]);
    }
  };

  stage(0, 0);
  __syncthreads();
  const int nk = KK >> 6;
  int cur = 0;
  for (int kt = 0; kt < nk; ++kt) {
    if (kt + 1 < nk) stage(cur ^ 1, (kt + 1) << 6);
    #pragma unroll
    for (int s = 0; s < 2; ++s) {
      bf16x8 a0 = *(const bf16x8*)&sA[cur][offA[0][s]];
      bf16x8 a1 = *(const bf16x8*)&sA[cur][offA[1][s]];
      bf16x8 b0 = *(const bf16x8*)&sB[cur][offB[0][s]];
      bf16x8 b1 = *(const bf16x8*)&sB[cur][offB[1][s]];
      acc[0][0] = __builtin_amdgcn_mfma_f32_16x16x32_bf16(a0, b0, acc[0][0], 0, 0, 0);
      acc[0][1] = __builtin_amdgcn_mfma_f32_16x16x32_bf16(a0, b1, acc[0][1], 0, 0, 0);
      acc[1][0] = __builtin_amdgcn_mfma_f32_16x16x32_bf16(a1, b0, acc[1][0], 0, 0, 0);
      acc[1][1] = __builtin_amdgcn_mfma_f32_16x16x32_bf16(a1, b1, acc[1][1], 0, 0, 0);
    }
    __syncthreads();
    cur ^= 1;
  }

  float lmax = 0.f;
  #pragma unroll
  for (int i = 0; i < 2; ++i)
    #pragma unroll
    for (int j = 0; j < 2; ++j)
      #pragma unroll
      for (int g = 0; g < 4; ++g) {
        int row = m0 + wr * 32 + i * 16 + (lane >> 4) * 4 + g;
        int col = n0 + wc * 32 + j * 16 + (lane & 15);
        if (row < M && col < N) {
          float v = acc[i][j][g];
          if (LEAKY) v = v > 0.f ? v : 0.1f * v;
          if (MAXOUT) lmax = fmaxf(lmax, v);
          if (OUTF32) ((float*)Cout)[(size_t)row * N + col] = v;
          else        ((__bf16*)Cout)[(size_t)row * N + col] = (__bf16)v;
        }
      }
  if (MAXOUT) {
    #pragma unroll
    for (int s = 32; s >= 1; s >>= 1) lmax = fmaxf(lmax, __shfl_xor(lmax, s, 64));
    if (lane == 0) s_max[wave] = lmax;
    __syncthreads();
    if (t == 0) {
      float mm = fmaxf(fmaxf(s_max[0], s_max[1]), fmaxf(s_max[2], s_max[3]));
      atomicMax(gmax, __float_as_uint(mm));
    }
  }
}

// ---------------- detection + fnorm; nnum==32 (neighbor row sums never exactly 0) ----------------
__global__ __launch_bounds__(256) void detect_kernel(
    const float* __restrict__ f6, const int* __restrict__ neigh,
    const float* __restrict__ gm_ptr, float* __restrict__ out_fnorm,
    float* __restrict__ out_scores, int N) {
  int n = blockIdx.x * 8 + (threadIdx.x >> 5);
  int c = threadIdx.x & 31;
  if (n >= N) return;
  float denom = gm_ptr[0] + 1e-6f;
  float fown = f6[(size_t)n * 32 + c];
  int idx_l = neigh[(size_t)n * 32 + c];
  float colsum = 0.f, colmax = -1e30f;
  for (int k = 0; k < 32; ++k) {
    int idx = __shfl(idx_l, k, 32);
    float v = f6[(size_t)idx * 32 + c];
    colsum += v;
    colmax = fmaxf(colmax, v);
  }
  float fs = fown / denom;
  float mean = (colsum / denom) * (1.f / 32.f);
  float x = fs - mean;
  float lms = fmaxf(x, 0.f) + log1pf(expf(-fabsf(x)));  // softplus
  float dm = fs;
  #pragma unroll
  for (int s = 16; s >= 1; s >>= 1) dm = fmaxf(dm, __shfl_xor(dm, s, 32));
  float as = lms * fs / (1e-6f + dm);
  float sc = as;
  #pragma unroll
  for (int s = 16; s >= 1; s >>= 1) sc = fmaxf(sc, __shfl_xor(sc, s, 32));
  float det = (fown == colmax) ? 1.f : 0.f;
  #pragma unroll
  for (int s = 16; s >= 1; s >>= 1) det = fmaxf(det, __shfl_xor(det, s, 32));
  float nn2 = fown * fown;
  #pragma unroll
  for (int s = 16; s >= 1; s >>= 1) nn2 += __shfl_xor(nn2, s, 32);
  float inv_nrm = 1.f / fmaxf(sqrtf(nn2), 1e-12f);
  out_fnorm[(size_t)n * 32 + c] = fown * inv_nrm;
  if (c == 0) out_scores[n] = sc * det;
}

extern "C" void kernel_launch(void* const* d_in, const int* in_sizes, int n_in,
                              void* d_out, int out_size, void* d_ws, size_t ws_size,
                              hipStream_t stream) {
  const float* features  = (const float*)d_in[0];
  const float* points0   = (const float*)d_in[1];
  const float* points1   = (const float*)d_in[2];
  const float* points2   = (const float*)d_in[3];
  const int* neighbors0  = (const int*)d_in[4];
  const int* neighbors1  = (const int*)d_in[5];
  const int* neighbors2  = (const int*)d_in[6];
  const int* pools0      = (const int*)d_in[7];
  const int* pools1      = (const int*)d_in[8];
  const int* upsamples0  = (const int*)d_in[9];
  const int* upsamples1  = (const int*)d_in[10];
  const float* kpoints   = (const float*)d_in[11];
  const float* W1  = (const float*)d_in[12];
  const float* W2  = (const float*)d_in[13];
  const float* W3  = (const float*)d_in[14];
  const float* W4  = (const float*)d_in[15];
  const float* W5  = (const float*)d_in[16];
  const float* Wu1 = (const float*)d_in[17];
  const float* Wu2 = (const float*)d_in[18];

  const float R0 = 0.5f;

  char* wp = (char*)d_ws;
  auto alloc = [&](size_t bytes) {
    char* r = wp;
    wp += (bytes + 255) & ~(size_t)255;
    return r;
  };
  __bf16* f0b  = (__bf16*)alloc((size_t)cN0 * 64 * 2);
  __bf16* f1b  = (__bf16*)alloc((size_t)cN1 * 64 * 2);
  __bf16* f2b  = (__bf16*)alloc((size_t)cN1 * 128 * 2);
  __bf16* f3b  = (__bf16*)alloc((size_t)cN2 * 128 * 2);
  __bf16* f4b  = (__bf16*)alloc((size_t)cN2 * 256 * 2);
  __bf16* f5b  = (__bf16*)alloc((size_t)cN1 * 128 * 2);
  float*  f6   = (float*)alloc((size_t)cN0 * 32 * 4);
  __bf16* WT2  = (__bf16*)alloc(960 * 64 * 2);
  __bf16* WT3  = (__bf16*)alloc(960 * 128 * 2);
  __bf16* WT4  = (__bf16*)alloc(1920 * 128 * 2);
  __bf16* WT5  = (__bf16*)alloc(1920 * 256 * 2);
  __bf16* WTu1 = (__bf16*)alloc(384 * 128 * 2);
  __bf16* WTu2 = (__bf16*)alloc(192 * 32 * 2);
  unsigned* gm = (unsigned*)alloc(256);
  float4* pk0  = (float4*)alloc((size_t)cN0 * 16);
  float4* pk1  = (float4*)alloc((size_t)cN1 * 16);
  float4* pk2  = (float4*)alloc((size_t)cN2 * 16);
  __bf16* fkb  = (__bf16*)alloc((size_t)cN1 * 960 * 2);

  prep_kernel<<<dim3(240, 9), 256, 0, stream>>>(
      points0, features, points1, points2, W2, W3, W4, W5, Wu1, Wu2,
      pk0, pk1, pk2, WT2, WT3, WT4, WT5, WTu1, WTu2);
  kpconv_l1<<<cN0 / 16, 256, 0, stream>>>(pk0, neighbors0, kpoints, W1, f0b, R0);

  // L2: strided, f0 -> f1 [N1,64]
  kpconv_agg_mfma<64, 8><<<cN1 / 8, 256, 0, stream>>>(pk1, pk0, pools0, f0b, kpoints, fkb, cN1, R0);
  gemm_mfma<true, false, false, false><<<dim3(1, 235), 256, 0, stream>>>(
      fkb, nullptr, nullptr, 0, WT2, f1b, cN1, 64, 960, nullptr);
  // L3: simple, f1 -> f2 [N1,128]
  kpconv_agg_mfma<64, 8><<<cN1 / 8, 256, 0, stream>>>(pk1, pk1, neighbors1, f1b, kpoints, fkb, cN1, 2.f * R0);
  gemm_mfma<true, false, false, false><<<dim3(2, 235), 256, 0, stream>>>(
      fkb, nullptr, nullptr, 0, WT3, f2b, cN1, 128, 960, nullptr);
  // L4: strided, f2 -> f3 [N2,128]
  kpconv_agg_mfma<128, 4><<<(cN2 + 3) / 4, 256, 0, stream>>>(pk2, pk1, pools1, f2b, kpoints, fkb, cN2, 2.f * R0);
  gemm_mfma<true, false, false, false><<<dim3(2, 59), 256, 0, stream>>>(
      fkb, nullptr, nullptr, 0, WT4, f3b, cN2, 128, 1920, nullptr);
  // L5: simple, f3 -> f4 [N2,256]
  kpconv_agg_mfma<128, 4><<<(cN2 + 3) / 4, 256, 0, stream>>>(pk2, pk2, neighbors2, f3b, kpoints, fkb, cN2, 4.f * R0);
  gemm_mfma<true, false, false, false><<<dim3(4, 59), 256, 0, stream>>>(
      fkb, nullptr, nullptr, 0, WT5, f4b, cN2, 256, 1920, nullptr);
  // D1: f5 = leaky(concat(f4[up1], f2) @ Wu1)
  gemm_mfma<true, true, false, false><<<dim3(2, 235), 256, 0, stream>>>(
      f4b, f2b, upsamples1, 256, WTu1, f5b, cN1, 128, 384, nullptr);
  // D2: f6 = concat(f5[up0], f0) @ Wu2  (f32 out, fused global max)
  hipMemsetAsync(gm, 0, 4, stream);
  gemm_mfma<false, true, true, true><<<dim3(1, 938), 256, 0, stream>>>(
      f5b, f0b, upsamples0, 128, WTu2, f6, cN0, 32, 192, gm);

  float* out_fnorm = (float*)d_out;
  float* out_scores = out_fnorm + (size_t)cN0 * 32;
  detect_kernel<<<(cN0 + 7) / 8, 256, 0, stream>>>(f6, neighbors0, (const float*)gm,
                                                   out_fnorm, out_scores, cN0);
}

// Round 6
// 219.140 us; speedup vs baseline: 4.0849x; 1.0251x over previous
//
#include <hip/hip_runtime.h>
#include <math.h>

static const int cN0 = 60000;
static const int cN1 = 15000;
static const int cN2 = 3750;

typedef __bf16 bf16x8 __attribute__((ext_vector_type(8)));
typedef float f32x4 __attribute__((ext_vector_type(4)));

#define GLOAD_LDS16(gsrc, ldst)                                                        \
  __builtin_amdgcn_global_load_lds((const __attribute__((address_space(1))) void*)(gsrc), \
                                   (__attribute__((address_space(3))) void*)(ldst), 16, 0, 0)

// ---------------- prep: pack points(+feat) into float4; transpose weights to bf16 ----------------
__global__ __launch_bounds__(256) void prep_kernel(
    const float* __restrict__ pts0, const float* __restrict__ feat,
    const float* __restrict__ pts1, const float* __restrict__ pts2,
    const float* __restrict__ W2, const float* __restrict__ W3, const float* __restrict__ W4,
    const float* __restrict__ W5, const float* __restrict__ Wu1, const float* __restrict__ Wu2,
    float4* __restrict__ pk0, float4* __restrict__ pk1, float4* __restrict__ pk2,
    __bf16* __restrict__ T2, __bf16* __restrict__ T3, __bf16* __restrict__ T4,
    __bf16* __restrict__ T5, __bf16* __restrict__ Tu1, __bf16* __restrict__ Tu2) {
  int role = blockIdx.y;
  int tid = blockIdx.x * 256 + threadIdx.x;
  int stride = gridDim.x * 256;
  if (role < 3) {
    const float* p = role == 0 ? pts0 : (role == 1 ? pts1 : pts2);
    float4* o = role == 0 ? pk0 : (role == 1 ? pk1 : pk2);
    int n = role == 0 ? cN0 : (role == 1 ? cN1 : cN2);
    for (int i = tid; i < n; i += stride) {
      float4 v;
      v.x = p[(size_t)i * 3 + 0];
      v.y = p[(size_t)i * 3 + 1];
      v.z = p[(size_t)i * 3 + 2];
      v.w = role == 0 ? feat[i] : 0.f;
      o[i] = v;
    }
  } else {
    const float* src;
    __bf16* dst;
    int Kd, Nd;
    switch (role) {
      case 3: src = W2;  dst = T2;  Kd = 960;  Nd = 64;  break;
      case 4: src = W3;  dst = T3;  Kd = 960;  Nd = 128; break;
      case 5: src = W4;  dst = T4;  Kd = 1920; Nd = 128; break;
      case 6: src = W5;  dst = T5;  Kd = 1920; Nd = 256; break;
      case 7: src = Wu1; dst = Tu1; Kd = 384;  Nd = 128; break;
      default: src = Wu2; dst = Tu2; Kd = 192; Nd = 32;  break;
    }
    int total = Kd * Nd;
    for (int e = tid; e < total; e += stride) {
      int n = e / Kd, k = e % Kd;
      dst[e] = (__bf16)src[(size_t)k * Nd + n];
    }
  }
}

// ---------------- L1 kpconv: Cin=1 -> 64, 16 points/block, packed float4 gather ----------------
__global__ __launch_bounds__(256) void kpconv_l1(
    const float4* __restrict__ pk, const int* __restrict__ neigh,
    const float* __restrict__ kpts, const float* __restrict__ W1,
    __bf16* __restrict__ f0, float extent) {
  const int t = threadIdx.x;
  const int n0b = blockIdx.x * 16;
  __shared__ float s_nb[32][16][4];   // [k][pt][xyzf]
  __shared__ float s_fk[16][16];      // [pt][p]
  __shared__ float s_W[960];
  for (int i = t; i < 960; i += 256) s_W[i] = W1[i];
  #pragma unroll
  for (int i = 0; i < 2; ++i) {
    int e = t + i * 256;
    int pt = e & 15, k = e >> 4;
    int idx = neigh[(size_t)(n0b + pt) * 32 + k];
    *(float4*)&s_nb[k][pt][0] = pk[idx];
  }
  __syncthreads();
  const int lane = t & 63, wave = t >> 6;
  const int g = lane >> 4, p_raw = lane & 15;
  const int p = p_raw < 15 ? p_raw : 0;
  const int pt = wave * 4 + g;
  const int n = n0b + pt;
  const float inv = 1.f / extent;
  float4 q = pk[n];
  const float kx = q.x + kpts[p * 3 + 0] * extent;
  const float ky = q.y + kpts[p * 3 + 1] * extent;
  const float kz = q.z + kpts[p * 3 + 2] * extent;
  float fk = 0.f;
  #pragma unroll 8
  for (int k = 0; k < 32; ++k) {
    f32x4 rec = *(const f32x4*)&s_nb[k][pt][0];
    float dx = rec[0] - kx, dy = rec[1] - ky, dz = rec[2] - kz;
    float d = sqrtf(dx * dx + dy * dy + dz * dz);
    fk += fmaxf(0.f, 1.f - d * inv) * rec[3];
  }
  if (p_raw < 15) s_fk[pt][p_raw] = fk;
  __syncthreads();
  #pragma unroll
  for (int o = 0; o < 4; ++o) {
    int e = o * 256 + t;
    int opt = e >> 6, c = e & 63;
    float acc = 0.f;
    #pragma unroll
    for (int pp = 0; pp < 15; ++pp) acc += s_fk[opt][pp] * s_W[pp * 64 + c];
    acc = acc > 0.f ? acc : 0.1f * acc;
    f0[(size_t)(n0b + opt) * 64 + c] = (__bf16)acc;
  }
}

// ---------------- FUSED kpconv layer: agg (LDS fk) + GEMM, no HBM fk round-trip ----------------
// Derived geometry: RPB=8192/CIN rows/batch, G=2 gathers/thread, NB=BM*32/RPB batches.
template <int CIN, int COUT, int BM, bool BDBUF>
__global__ __launch_bounds__(512) void kpconv_fused(
    const float4* __restrict__ qp, const float4* __restrict__ sp,
    const int* __restrict__ neigh, const __bf16* __restrict__ F,
    const float* __restrict__ kpts, const __bf16* __restrict__ BT,
    __bf16* __restrict__ out, int M, float extent) {
  constexpr int KK = 15 * CIN;        // 960 / 1920
  constexpr int KT = KK / 64;
  constexpr int CPRow = CIN / 8;      // 16B chunks per F row: 8 / 16
  constexpr int RPB = 8192 / CIN;     // rows per batch: 128 / 64
  constexpr int GS = RPB / 2;         // gather row stride: 64 / 32
  constexpr int BP = RPB / 32;        // points per batch: 4 / 2
  constexpr int NB = BM * 32 / RPB;   // batches: 16 (BM=64,CIN=64) / 8 (BM=16,CIN=128)
  constexpr int WPP = 8 / BP;         // waves per point in agg
  constexpr int FBUF = 8192;          // staged elems per batch (both configs)
  constexpr int RG = BM / 16;         // phase2 row groups
  constexpr int CG = 8 / RG;          // phase2 col groups
  constexpr int NJ = COUT / (16 * CG);
  constexpr int SMEM_FK = BM * KK * 2;
  constexpr int SMEM = SMEM_FK + BP * 1280 + BM * 16 + 2 * FBUF * 2;

  __shared__ __align__(16) char smem[SMEM];
  __bf16* s_fk   = (__bf16*)smem;                                   // [BM][KK] chunk-swizzled
  __bf16* s_infl = (__bf16*)(smem + SMEM_FK);                       // [BP][16][40]
  float4* s_q    = (float4*)(smem + SMEM_FK + BP * 1280);           // [BM]
  __bf16* s_F    = (__bf16*)(smem + SMEM_FK + BP * 1280 + BM * 16); // [2][FBUF] ping-pong
  __bf16* s_B    = s_F;                                             // phase 2 reuse

  const int t = threadIdx.x;
  const int w = t >> 6, l = t & 63;
  const int c16 = l & 15, g4 = l >> 4;
  const int m0 = blockIdx.x * BM;
  const int* nb_base = neigh + (size_t)m0 * 32;
  int rlim = (M - m0) * 32 - 1;
  if (rlim > BM * 32 - 1) rlim = BM * 32 - 1;

  // ---- gather/infl thread mapping ----
  const int gb = t / CPRow;          // row group within batch
  const int ch = t % CPRow;          // 16B chunk within row
  int idxg[NB][2];
  #pragma unroll
  for (int b = 0; b < NB; ++b)
    #pragma unroll
    for (int j = 0; j < 2; ++j) {
      int r = b * RPB + gb + j * GS;
      idxg[b][j] = nb_base[r < rlim ? r : rlim];
    }
  const int ii  = t & 1;
  const int pq4 = ((t >> 1) & 3) * 4;
  const int row_i = gb + ii * GS;    // my infl row (0..RPB-1)
  const int pt_i = row_i >> 5, kk_i = row_i & 31;
  const float inv = 1.f / extent;
  float kpx[4], kpy[4], kpz[4];
  #pragma unroll
  for (int pi = 0; pi < 4; ++pi) {
    int p = pq4 + pi; if (p > 14) p = 14;
    kpx[pi] = kpts[p * 3 + 0] * extent;
    kpy[pi] = kpts[p * 3 + 1] * extent;
    kpz[pi] = kpts[p * 3 + 2] * extent;
  }
  if (t < BM) { int n = m0 + t; s_q[t] = qp[n < M ? n : M - 1]; }

  auto stageF = [&](int buf, const int (&ig)[2]) {
    #pragma unroll
    for (int j = 0; j < 2; ++j) {
      int k = (gb + j * GS) & 31;
      const __bf16* src = F + (size_t)ig[j] * CIN + (ch ^ ((k >> 3) & 3)) * 8;
      GLOAD_LDS16(src, s_F + buf * FBUF + (j * 512 + t) * 8);
    }
  };
  auto inflC = [&](const float4& spv, int b, float (&v)[4]) {
    float4 q = s_q[b * BP + pt_i];
    float sx = spv.x - q.x, sy = spv.y - q.y, sz = spv.z - q.z;
    #pragma unroll
    for (int pi = 0; pi < 4; ++pi) {
      float dx = sx - kpx[pi], dy = sy - kpy[pi], dz = sz - kpz[pi];
      float d = sqrtf(dx * dx + dy * dy + dz * dz);
      v[pi] = fmaxf(0.f, 1.f - d * inv);
    }
  };
  auto inflStore = [&](const float (&v)[4]) {
    #pragma unroll
    for (int pi = 0; pi < 4; ++pi) {
      int p = pq4 + pi;
      if (p < 15) s_infl[pt_i * 640 + p * 40 + kk_i] = (__bf16)v[pi];
    }
  };
  auto mfmaBatch = [&](int b, int buf) {
    const int pt_loc = w / WPP;
    const int cc0 = (w % WPP) * 2;
    const __bf16* Fb = s_F + buf * FBUF + pt_loc * (32 * CIN);
    bf16x8 a = *(const bf16x8*)&s_infl[pt_loc * 640 + c16 * 40 + g4 * 8];
    const int row = b * BP + pt_loc;
    #pragma unroll
    for (int ci = 0; ci < 2; ++ci) {
      const int cc = cc0 + ci;
      const int Lc = cc * 2 + (c16 >> 3);
      const int pc = Lc ^ g4;  // inverse of the stage-side low-2-bit XOR
      bf16x8 bv;
      #pragma unroll
      for (int j = 0; j < 8; ++j)
        bv[j] = Fb[(g4 * 8 + j) * CIN + pc * 8 + (c16 & 7)];
      f32x4 acc = __builtin_amdgcn_mfma_f32_16x16x32_bf16(a, bv, (f32x4){0.f, 0.f, 0.f, 0.f}, 0, 0, 0);
      #pragma unroll
      for (int r = 0; r < 4; ++r) {
        int p = g4 * 4 + r;
        if (p < 15) {
          int Lf = p * CPRow + Lc;
          int phys = (Lf & ~7) | ((Lf & 7) ^ (row & 7));
          s_fk[(size_t)row * KK + phys * 8 + (c16 & 7)] = (__bf16)acc[r];
        }
      }
    }
  };

  // publish s_q before infl reads it
  asm volatile("s_waitcnt lgkmcnt(0)" ::: "memory");
  __builtin_amdgcn_s_barrier();
  __builtin_amdgcn_sched_barrier(0);

  // ---- phase 1: pipelined agg (3 vmem ops/iter; vmcnt(3) => batch-b staging drained) ----
  float4 spc, spn;
  {
    float4 sp0 = sp[idxg[0][ii]];
    stageF(0, idxg[0]);
    spc = sp[idxg[NB > 1 ? 1 : 0][ii]];
    float v0[4];
    inflC(sp0, 0, v0);
    inflStore(v0);
  }
  __builtin_amdgcn_sched_barrier(0);
  #pragma unroll
  for (int b = 0; b < NB; ++b) {
    if (b + 1 < NB) stageF((b + 1) & 1, idxg[b + 1]);
    if (b + 2 < NB) spn = sp[idxg[b + 2][ii]];
    float vn[4];
    if (b + 1 < NB) inflC(spc, b + 1, vn);
    if (b + 1 < NB) { asm volatile("s_waitcnt vmcnt(3)" ::: "memory"); }
    else            { asm volatile("s_waitcnt vmcnt(0)" ::: "memory"); }
    asm volatile("s_waitcnt lgkmcnt(0)" ::: "memory");
    __builtin_amdgcn_s_barrier();
    __builtin_amdgcn_sched_barrier(0);
    mfmaBatch(b, b & 1);
    asm volatile("s_waitcnt lgkmcnt(0)" ::: "memory");
    __builtin_amdgcn_s_barrier();
    __builtin_amdgcn_sched_barrier(0);
    if (b + 1 < NB) { inflStore(vn); spc = spn; }
  }
  __syncthreads();

  // ---- phase 2: GEMM fk[BM][KK] x BT[COUT][KK]^T ----
  const int wr = w / CG, wc = w % CG;
  f32x4 acc[NJ];
  #pragma unroll
  for (int j = 0; j < NJ; ++j) acc[j] = (f32x4){0.f, 0.f, 0.f, 0.f};
  auto stageB = [&](int buf, int kt) {
    #pragma unroll
    for (int rnd = 0; rnd < COUT / 64; ++rnd) {
      int slot = rnd * 512 + t;
      int row = slot >> 3, bch = slot & 7;
      GLOAD_LDS16(BT + (size_t)row * KK + kt * 64 + (bch ^ (row & 7)) * 8,
                  s_B + buf * (COUT * 64) + slot * 8);
    }
  };
  const __bf16* fkrow = s_fk + (size_t)(wr * 16 + c16) * KK;
  auto computeTile = [&](int kt, int buf) {
    bf16x8 af[2];
    #pragma unroll
    for (int s = 0; s < 2; ++s)
      af[s] = *(const bf16x8*)&fkrow[((kt * 8 + (s * 4 + g4)) & ~7 | (((s * 4 + g4) & 7) ^ (c16 & 7))) * 8 + (kt * 8 & ~7) * 0];
    // NOTE: kt*8 is chunk-aligned (multiple of 8), so phys = kt*8 + ((s*4+g4) ^ (c16&7))
    #pragma unroll
    for (int s = 0; s < 2; ++s)
      af[s] = *(const bf16x8*)&fkrow[(kt * 8 + ((s * 4 + g4) ^ (c16 & 7))) * 8];
    const __bf16* Bb = s_B + buf * (COUT * 64);
    #pragma unroll
    for (int j = 0; j < NJ; ++j) {
      int n = wc * (16 * NJ) + j * 16 + c16;
      #pragma unroll
      for (int s = 0; s < 2; ++s) {
        bf16x8 bf = *(const bf16x8*)&Bb[n * 64 + ((s * 4 + g4) ^ (n & 7)) * 8];
        acc[j] = __builtin_amdgcn_mfma_f32_16x16x32_bf16(af[s], bf, acc[j], 0, 0, 0);
      }
    }
  };
  if (BDBUF) {
    stageB(0, 0);
    __syncthreads();
    for (int kt = 0; kt < KT; ++kt) {
      if (kt + 1 < KT) stageB((kt + 1) & 1, kt + 1);
      computeTile(kt, kt & 1);
      __syncthreads();
    }
  } else {
    for (int kt = 0; kt < KT; ++kt) {
      stageB(0, kt);
      __syncthreads();
      computeTile(kt, 0);
      __syncthreads();
    }
  }
  // ---- epilogue ----
  #pragma unroll
  for (int j = 0; j < NJ; ++j)
    #pragma unroll
    for (int r = 0; r < 4; ++r) {
      int row = m0 + wr * 16 + g4 * 4 + r;
      int col = wc * (16 * NJ) + j * 16 + c16;
      if (row < M) {
        float v = acc[j][r];
        v = v > 0.f ? v : 0.1f * v;
        out[(size_t)row * COUT + col] = (__bf16)v;
      }
    }
}

// ---------------- MFMA bf16 GEMM: C[M,N] = Aeff[M,KK] * BT[N,KK]^T (decoder) ----------------
template <bool LEAKY, bool GATHER, bool OUTF32, bool MAXOUT>
__global__ __launch_bounds__(256, 2) void gemm_mfma(
    const __bf16* __restrict__ A1, const __bf16* __restrict__ A2,
    const int* __restrict__ gidx, const int K1,
    const __bf16* __restrict__ BT, void* __restrict__ Cout,
    const int M, const int N, const int KK, unsigned* __restrict__ gmax) {
  __shared__ __bf16 sA[2][4096];
  __shared__ __bf16 sB[2][4096];
  __shared__ float s_max[4];
  const int t = threadIdx.x;
  const int lane = t & 63, wave = t >> 6;
  const int wr = wave >> 1, wc = wave & 1;
  const int m0 = blockIdx.y * 64, n0 = blockIdx.x * 64;
  const int K2 = KK - K1;

  const __bf16* a1row[2];
  const __bf16* a2row[2];
  const __bf16* brow_[2];
  int csrc[2], wbase[2];
  #pragma unroll
  for (int r = 0; r < 2; ++r) {
    int slot = r * 256 + wave * 64 + lane;
    int row = slot >> 3;
    csrc[r] = ((slot & 7) ^ (row & 7)) * 8;
    wbase[r] = (r * 256 + wave * 64) * 8;
    int gm = m0 + row; if (gm > M - 1) gm = M - 1;
    if (GATHER) {
      a1row[r] = A1 + (size_t)gidx[gm] * K1;
      a2row[r] = A2 + (size_t)gm * (size_t)K2;
    } else {
      a1row[r] = A1 + (size_t)gm * (size_t)KK;
    }
    int gn = n0 + row; if (gn > N - 1) gn = N - 1;
    brow_[r] = BT + (size_t)gn * (size_t)KK;
  }

  int offA[2][2], offB[2][2];
  #pragma unroll
  for (int i = 0; i < 2; ++i)
    #pragma unroll
    for (int s = 0; s < 2; ++s) {
      int ra = wr * 32 + i * 16 + (lane & 15);
      int rb = wc * 32 + i * 16 + (lane & 15);
      int chn = s * 4 + (lane >> 4);
      offA[i][s] = ra * 64 + (chn ^ (ra & 7)) * 8;
      offB[i][s] = rb * 64 + (chn ^ (rb & 7)) * 8;
    }

  f32x4 acc[2][2];
  #pragma unroll
  for (int i = 0; i < 2; ++i)
    #pragma unroll
    for (int j = 0; j < 2; ++j) acc[i][j] = (f32x4){0.f, 0.f, 0.f, 0.f};

  auto stage = [&](int buf, int k0) {
    #pragma unroll
    for (int r = 0; r < 2; ++r) {
      int kg = k0 + csrc[r];
      const __bf16* asrc;
      if (GATHER) asrc = (kg < K1) ? (a1row[r] + kg) : (a2row[r] + (kg - K1));
      else        asrc = a1row[r] + kg;
      GLOAD_LDS16(asrc, &sA[buf][wbase[r]]);
      GLOAD_LDS16(brow_[r] + kg, &sB[buf][wbase[r]]);
    }
  };

  stage(0, 0);
  __syncthreads();
  const int nk = KK >> 6;
  int cur = 0;
  for (int kt = 0; kt < nk; ++kt) {
    if (kt + 1 < nk) stage(cur ^ 1, (kt + 1) << 6);
    #pragma unroll
    for (int s = 0; s < 2; ++s) {
      bf16x8 a0 = *(const bf16x8*)&sA[cur][offA[0][s]];
      bf16x8 a1 = *(const bf16x8*)&sA[cur][offA[1][s]];
      bf16x8 b0 = *(const bf16x8*)&sB[cur][offB[0][s]];
      bf16x8 b1 = *(const bf16x8*)&sB[cur][offB[1][s]];
      acc[0][0] = __builtin_amdgcn_mfma_f32_16x16x32_bf16(a0, b0, acc[0][0], 0, 0, 0);
      acc[0][1] = __builtin_amdgcn_mfma_f32_16x16x32_bf16(a0, b1, acc[0][1], 0, 0, 0);
      acc[1][0] = __builtin_amdgcn_mfma_f32_16x16x32_bf16(a1, b0, acc[1][0], 0, 0, 0);
      acc[1][1] = __builtin_amdgcn_mfma_f32_16x16x32_bf16(a1, b1, acc[1][1], 0, 0, 0);
    }
    __syncthreads();
    cur ^= 1;
  }

  float lmax = 0.f;
  #pragma unroll
  for (int i = 0; i < 2; ++i)
    #pragma unroll
    for (int j = 0; j < 2; ++j)
      #pragma unroll
      for (int g = 0; g < 4; ++g) {
        int row = m0 + wr * 32 + i * 16 + (lane >> 4) * 4 + g;
        int col = n0 + wc * 32 + j * 16 + (lane & 15);
        if (row < M && col < N) {
          float v = acc[i][j][g];
          if (LEAKY) v = v > 0.f ? v : 0.1f * v;
          if (MAXOUT) lmax = fmaxf(lmax, v);
          if (OUTF32) ((float*)Cout)[(size_t)row * N + col] = v;
          else        ((__bf16*)Cout)[(size_t)row * N + col] = (__bf16)v;
        }
      }
  if (MAXOUT) {
    #pragma unroll
    for (int s = 32; s >= 1; s >>= 1) lmax = fmaxf(lmax, __shfl_xor(lmax, s, 64));
    if (lane == 0) s_max[wave] = lmax;
    __syncthreads();
    if (t == 0) {
      float mm = fmaxf(fmaxf(s_max[0], s_max[1]), fmaxf(s_max[2], s_max[3]));
      atomicMax(gmax, __float_as_uint(mm));
    }
  }
}

// ---------------- detection + fnorm; nnum==32 (neighbor row sums never exactly 0) ----------------
__global__ __launch_bounds__(256) void detect_kernel(
    const float* __restrict__ f6, const int* __restrict__ neigh,
    const float* __restrict__ gm_ptr, float* __restrict__ out_fnorm,
    float* __restrict__ out_scores, int N) {
  int n = blockIdx.x * 8 + (threadIdx.x >> 5);
  int c = threadIdx.x & 31;
  if (n >= N) return;
  float denom = gm_ptr[0] + 1e-6f;
  float fown = f6[(size_t)n * 32 + c];
  int idx_l = neigh[(size_t)n * 32 + c];
  float colsum = 0.f, colmax = -1e30f;
  for (int k = 0; k < 32; ++k) {
    int idx = __shfl(idx_l, k, 32);
    float v = f6[(size_t)idx * 32 + c];
    colsum += v;
    colmax = fmaxf(colmax, v);
  }
  float fs = fown / denom;
  float mean = (colsum / denom) * (1.f / 32.f);
  float x = fs - mean;
  float lms = fmaxf(x, 0.f) + log1pf(expf(-fabsf(x)));  // softplus
  float dm = fs;
  #pragma unroll
  for (int s = 16; s >= 1; s >>= 1) dm = fmaxf(dm, __shfl_xor(dm, s, 32));
  float as = lms * fs / (1e-6f + dm);
  float sc = as;
  #pragma unroll
  for (int s = 16; s >= 1; s >>= 1) sc = fmaxf(sc, __shfl_xor(sc, s, 32));
  float det = (fown == colmax) ? 1.f : 0.f;
  #pragma unroll
  for (int s = 16; s >= 1; s >>= 1) det = fmaxf(det, __shfl_xor(det, s, 32));
  float nn2 = fown * fown;
  #pragma unroll
  for (int s = 16; s >= 1; s >>= 1) nn2 += __shfl_xor(nn2, s, 32);
  float inv_nrm = 1.f / fmaxf(sqrtf(nn2), 1e-12f);
  out_fnorm[(size_t)n * 32 + c] = fown * inv_nrm;
  if (c == 0) out_scores[n] = sc * det;
}

extern "C" void kernel_launch(void* const* d_in, const int* in_sizes, int n_in,
                              void* d_out, int out_size, void* d_ws, size_t ws_size,
                              hipStream_t stream) {
  const float* features  = (const float*)d_in[0];
  const float* points0   = (const float*)d_in[1];
  const float* points1   = (const float*)d_in[2];
  const float* points2   = (const float*)d_in[3];
  const int* neighbors0  = (const int*)d_in[4];
  const int* neighbors1  = (const int*)d_in[5];
  const int* neighbors2  = (const int*)d_in[6];
  const int* pools0      = (const int*)d_in[7];
  const int* pools1      = (const int*)d_in[8];
  const int* upsamples0  = (const int*)d_in[9];
  const int* upsamples1  = (const int*)d_in[10];
  const float* kpoints   = (const float*)d_in[11];
  const float* W1  = (const float*)d_in[12];
  const float* W2  = (const float*)d_in[13];
  const float* W3  = (const float*)d_in[14];
  const float* W4  = (const float*)d_in[15];
  const float* W5  = (const float*)d_in[16];
  const float* Wu1 = (const float*)d_in[17];
  const float* Wu2 = (const float*)d_in[18];

  const float R0 = 0.5f;

  char* wp = (char*)d_ws;
  auto alloc = [&](size_t bytes) {
    char* r = wp;
    wp += (bytes + 255) & ~(size_t)255;
    return r;
  };
  __bf16* f0b  = (__bf16*)alloc((size_t)cN0 * 64 * 2);
  __bf16* f1b  = (__bf16*)alloc((size_t)cN1 * 64 * 2);
  __bf16* f2b  = (__bf16*)alloc((size_t)cN1 * 128 * 2);
  __bf16* f3b  = (__bf16*)alloc((size_t)cN2 * 128 * 2);
  __bf16* f4b  = (__bf16*)alloc((size_t)cN2 * 256 * 2);
  __bf16* f5b  = (__bf16*)alloc((size_t)cN1 * 128 * 2);
  float*  f6   = (float*)alloc((size_t)cN0 * 32 * 4);
  __bf16* WT2  = (__bf16*)alloc(960 * 64 * 2);
  __bf16* WT3  = (__bf16*)alloc(960 * 128 * 2);
  __bf16* WT4  = (__bf16*)alloc(1920 * 128 * 2);
  __bf16* WT5  = (__bf16*)alloc(1920 * 256 * 2);
  __bf16* WTu1 = (__bf16*)alloc(384 * 128 * 2);
  __bf16* WTu2 = (__bf16*)alloc(192 * 32 * 2);
  unsigned* gm = (unsigned*)alloc(256);
  float4* pk0  = (float4*)alloc((size_t)cN0 * 16);
  float4* pk1  = (float4*)alloc((size_t)cN1 * 16);
  float4* pk2  = (float4*)alloc((size_t)cN2 * 16);

  prep_kernel<<<dim3(240, 9), 256, 0, stream>>>(
      points0, features, points1, points2, W2, W3, W4, W5, Wu1, Wu2,
      pk0, pk1, pk2, WT2, WT3, WT4, WT5, WTu1, WTu2);
  kpconv_l1<<<cN0 / 16, 256, 0, stream>>>(pk0, neighbors0, kpoints, W1, f0b, R0);

  // L2: strided, f0 -> f1 [N1,64]
  kpconv_fused<64, 64, 64, true><<<(cN1 + 63) / 64, 512, 0, stream>>>(
      pk1, pk0, pools0, f0b, kpoints, WT2, f1b, cN1, R0);
  // L3: simple, f1 -> f2 [N1,128]
  kpconv_fused<64, 128, 64, true><<<(cN1 + 63) / 64, 512, 0, stream>>>(
      pk1, pk1, neighbors1, f1b, kpoints, WT3, f2b, cN1, 2.f * R0);
  // L4: strided, f2 -> f3 [N2,128]
  kpconv_fused<128, 128, 16, true><<<(cN2 + 15) / 16, 512, 0, stream>>>(
      pk2, pk1, pools1, f2b, kpoints, WT4, f3b, cN2, 2.f * R0);
  // L5: simple, f3 -> f4 [N2,256]
  kpconv_fused<128, 256, 16, false><<<(cN2 + 15) / 16, 512, 0, stream>>>(
      pk2, pk2, neighbors2, f3b, kpoints, WT5, f4b, cN2, 4.f * R0);

  // D1: f5 = leaky(concat(f4[up1], f2) @ Wu1)
  gemm_mfma<true, true, false, false><<<dim3(2, 235), 256, 0, stream>>>(
      f4b, f2b, upsamples1, 256, WTu1, f5b, cN1, 128, 384, nullptr);
  // D2: f6 = concat(f5[up0], f0) @ Wu2  (f32 out, fused global max)
  hipMemsetAsync(gm, 0, 4, stream);
  gemm_mfma<false, true, true, true><<<dim3(1, 938), 256, 0, stream>>>(
      f5b, f0b, upsamples0, 128, WTu2, f6, cN0, 32, 192, gm);

  float* out_fnorm = (float*)d_out;
  float* out_scores = out_fnorm + (size_t)cN0 * 32;
  detect_kernel<<<(cN0 + 7) / 8, 256, 0, stream>>>(f6, neighbors0, (const float*)gm,
                                                   out_fnorm, out_scores, cN0);
}

// Round 7
// 205.065 us; speedup vs baseline: 4.3653x; 1.0686x over previous
//
#include <hip/hip_runtime.h>
#include <math.h>

static const int cN0 = 60000;
static const int cN1 = 15000;
static const int cN2 = 3750;

typedef __bf16 bf16x8 __attribute__((ext_vector_type(8)));
typedef float f32x4 __attribute__((ext_vector_type(4)));

#define GLOAD_LDS16(gsrc, ldst)                                                        \
  __builtin_amdgcn_global_load_lds((const __attribute__((address_space(1))) void*)(gsrc), \
                                   (__attribute__((address_space(3))) void*)(ldst), 16, 0, 0)

// ---------------- prep: pack points(+feat) into float4; transpose weights to bf16 ----------------
__global__ __launch_bounds__(256) void prep_kernel(
    const float* __restrict__ pts0, const float* __restrict__ feat,
    const float* __restrict__ pts1, const float* __restrict__ pts2,
    const float* __restrict__ W2, const float* __restrict__ W3, const float* __restrict__ W4,
    const float* __restrict__ W5, const float* __restrict__ Wu1, const float* __restrict__ Wu2,
    float4* __restrict__ pk0, float4* __restrict__ pk1, float4* __restrict__ pk2,
    __bf16* __restrict__ T2, __bf16* __restrict__ T3, __bf16* __restrict__ T4,
    __bf16* __restrict__ T5, __bf16* __restrict__ Tu1, __bf16* __restrict__ Tu2) {
  int role = blockIdx.y;
  int tid = blockIdx.x * 256 + threadIdx.x;
  int stride = gridDim.x * 256;
  if (role < 3) {
    const float* p = role == 0 ? pts0 : (role == 1 ? pts1 : pts2);
    float4* o = role == 0 ? pk0 : (role == 1 ? pk1 : pk2);
    int n = role == 0 ? cN0 : (role == 1 ? cN1 : cN2);
    for (int i = tid; i < n; i += stride) {
      float4 v;
      v.x = p[(size_t)i * 3 + 0];
      v.y = p[(size_t)i * 3 + 1];
      v.z = p[(size_t)i * 3 + 2];
      v.w = role == 0 ? feat[i] : 0.f;
      o[i] = v;
    }
  } else {
    const float* src;
    __bf16* dst;
    int Kd, Nd;
    switch (role) {
      case 3: src = W2;  dst = T2;  Kd = 960;  Nd = 64;  break;
      case 4: src = W3;  dst = T3;  Kd = 960;  Nd = 128; break;
      case 5: src = W4;  dst = T4;  Kd = 1920; Nd = 128; break;
      case 6: src = W5;  dst = T5;  Kd = 1920; Nd = 256; break;
      case 7: src = Wu1; dst = Tu1; Kd = 384;  Nd = 128; break;
      default: src = Wu2; dst = Tu2; Kd = 192; Nd = 32;  break;
    }
    int total = Kd * Nd;
    for (int e = tid; e < total; e += stride) {
      int n = e / Kd, k = e % Kd;
      dst[e] = (__bf16)src[(size_t)k * Nd + n];
    }
  }
}

// ---------------- L1 kpconv: Cin=1 -> 64, 16 points/block, packed float4 gather ----------------
__global__ __launch_bounds__(256) void kpconv_l1(
    const float4* __restrict__ pk, const int* __restrict__ neigh,
    const float* __restrict__ kpts, const float* __restrict__ W1,
    __bf16* __restrict__ f0, float extent) {
  const int t = threadIdx.x;
  const int n0b = blockIdx.x * 16;
  __shared__ float s_nb[32][16][4];   // [k][pt][xyzf]
  __shared__ float s_fk[16][16];      // [pt][p]
  __shared__ float s_W[960];
  for (int i = t; i < 960; i += 256) s_W[i] = W1[i];
  #pragma unroll
  for (int i = 0; i < 2; ++i) {
    int e = t + i * 256;
    int pt = e & 15, k = e >> 4;
    int idx = neigh[(size_t)(n0b + pt) * 32 + k];
    *(float4*)&s_nb[k][pt][0] = pk[idx];
  }
  __syncthreads();
  const int lane = t & 63, wave = t >> 6;
  const int g = lane >> 4, p_raw = lane & 15;
  const int p = p_raw < 15 ? p_raw : 0;
  const int pt = wave * 4 + g;
  const int n = n0b + pt;
  const float inv = 1.f / extent;
  float4 q = pk[n];
  const float kx = q.x + kpts[p * 3 + 0] * extent;
  const float ky = q.y + kpts[p * 3 + 1] * extent;
  const float kz = q.z + kpts[p * 3 + 2] * extent;
  float fk = 0.f;
  #pragma unroll 8
  for (int k = 0; k < 32; ++k) {
    f32x4 rec = *(const f32x4*)&s_nb[k][pt][0];
    float dx = rec[0] - kx, dy = rec[1] - ky, dz = rec[2] - kz;
    float d = sqrtf(dx * dx + dy * dy + dz * dz);
    fk += fmaxf(0.f, 1.f - d * inv) * rec[3];
  }
  if (p_raw < 15) s_fk[pt][p_raw] = fk;
  __syncthreads();
  #pragma unroll
  for (int o = 0; o < 4; ++o) {
    int e = o * 256 + t;
    int opt = e >> 6, c = e & 63;
    float acc = 0.f;
    #pragma unroll
    for (int pp = 0; pp < 15; ++pp) acc += s_fk[opt][pp] * s_W[pp * 64 + c];
    acc = acc > 0.f ? acc : 0.1f * acc;
    f0[(size_t)(n0b + opt) * 64 + c] = (__bf16)acc;
  }
}

// ---------------- FUSED kpconv layer: agg (LDS fk) + GEMM ----------------
// RPB=64 rows/batch always; G=CIN/64 gathers/thread; BP=2 pts/batch; NB=BM/2 batches.
// L2/L3 (BM=32): 79KB LDS -> 2 blocks/CU.
template <int CIN, int COUT, int BM, bool BDBUF>
__global__ __launch_bounds__(512) void kpconv_fused(
    const float4* __restrict__ qp, const float4* __restrict__ sp,
    const int* __restrict__ neigh, const __bf16* __restrict__ F,
    const float* __restrict__ kpts, const __bf16* __restrict__ BT,
    __bf16* __restrict__ out, int M, float extent) {
  constexpr int KK = 15 * CIN;
  constexpr int KT = KK / 64;
  constexpr int CPRow = CIN / 8;      // 16B chunks per F row: 8 / 16
  constexpr int G = CIN / 64;         // gathers per thread per batch: 1 / 2
  constexpr int GS = 64 / G;          // gather row stride
  constexpr int NB = BM / 2;          // batches (64 rows = 2 points each)
  constexpr int CPW = CIN / 64;       // col 16-chunks per wave in agg mfma
  constexpr int FBUF = 64 * CIN;      // staged elems per batch
  constexpr int RG = BM / 16;         // phase2 row groups
  constexpr int CG = 8 / RG;          // phase2 col groups
  constexpr int NJ = COUT / (16 * CG);
  constexpr int SMEM_FK = BM * KK * 2;
  constexpr int SMEM = SMEM_FK + 2 * 1280 + BM * 16 + 2 * FBUF * 2;

  __shared__ __align__(16) char smem[SMEM];
  __bf16* s_fk   = (__bf16*)smem;                                   // [BM][KK] chunk-swizzled
  __bf16* s_infl = (__bf16*)(smem + SMEM_FK);                       // [2][16][40]
  float4* s_q    = (float4*)(smem + SMEM_FK + 2 * 1280);            // [BM]
  __bf16* s_F    = (__bf16*)(smem + SMEM_FK + 2 * 1280 + BM * 16);  // [2][FBUF] ping-pong
  __bf16* s_B    = s_F;                                             // phase 2 reuse

  const int t = threadIdx.x;
  const int w = t >> 6, l = t & 63;
  const int c16 = l & 15, g4 = l >> 4;
  const int m0 = blockIdx.x * BM;
  const int* nb_base = neigh + (size_t)m0 * 32;
  int rlim = (M - m0) * 32 - 1;
  if (rlim > BM * 32 - 1) rlim = BM * 32 - 1;

  // ---- gather mapping: thread stages G rows' chunks ----
  const int gb = t / CPRow;          // row group within batch
  const int ch = t % CPRow;          // 16B chunk within row
  int idxg[NB][G];
  #pragma unroll
  for (int b = 0; b < NB; ++b)
    #pragma unroll
    for (int j = 0; j < G; ++j) {
      int r = b * 64 + gb + j * GS;
      idxg[b][j] = nb_base[r < rlim ? r : rlim];
    }
  // ---- infl mapping: t<256 threads own (row 0..63) x (4 kernel pts); rest redundant ----
  const int row_i = (t >> 2) & 63;
  const int pq4 = (t & 3) * 4;
  const int pt_i = row_i >> 5, kk_i = row_i & 31;
  int idxi[NB];
  #pragma unroll
  for (int b = 0; b < NB; ++b) {
    int r = b * 64 + row_i;
    idxi[b] = nb_base[r < rlim ? r : rlim];
  }
  const float inv = 1.f / extent;
  float kpx[4], kpy[4], kpz[4];
  #pragma unroll
  for (int pi = 0; pi < 4; ++pi) {
    int p = pq4 + pi; if (p > 14) p = 14;
    kpx[pi] = kpts[p * 3 + 0] * extent;
    kpy[pi] = kpts[p * 3 + 1] * extent;
    kpz[pi] = kpts[p * 3 + 2] * extent;
  }
  if (t < BM) { int n = m0 + t; s_q[t] = qp[n < M ? n : M - 1]; }

  auto stageF = [&](int buf, const int (&ig)[G]) {
    #pragma unroll
    for (int j = 0; j < G; ++j) {
      int k = (gb + j * GS) & 31;
      const __bf16* src = F + (size_t)ig[j] * CIN + (ch ^ ((k >> 3) & 3)) * 8;
      GLOAD_LDS16(src, s_F + buf * FBUF + (j * 512 + t) * 8);
    }
  };
  auto inflC = [&](const float4& spv, int b, float (&v)[4]) {
    float4 q = s_q[b * 2 + pt_i];
    float sx = spv.x - q.x, sy = spv.y - q.y, sz = spv.z - q.z;
    #pragma unroll
    for (int pi = 0; pi < 4; ++pi) {
      float dx = sx - kpx[pi], dy = sy - kpy[pi], dz = sz - kpz[pi];
      float d = sqrtf(dx * dx + dy * dy + dz * dz);
      v[pi] = fmaxf(0.f, 1.f - d * inv);
    }
  };
  auto inflStore = [&](const float (&v)[4]) {
    if (t < 256) {
      #pragma unroll
      for (int pi = 0; pi < 4; ++pi) {
        int p = pq4 + pi;
        if (p < 15) s_infl[pt_i * 640 + p * 40 + kk_i] = (__bf16)v[pi];
      }
    }
  };
  auto mfmaBatch = [&](int b, int buf) {
    const int pt_loc = w / 4;          // 0..1
    const int cc0 = (w & 3) * CPW;
    const __bf16* Fb = s_F + buf * FBUF + pt_loc * (32 * CIN);
    bf16x8 a = *(const bf16x8*)&s_infl[pt_loc * 640 + c16 * 40 + g4 * 8];
    const int row = b * 2 + pt_loc;
    #pragma unroll
    for (int ci = 0; ci < CPW; ++ci) {
      const int cc = cc0 + ci;
      const int Lc = cc * 2 + (c16 >> 3);
      const int pc = Lc ^ g4;          // inverse of stage-side low-2-bit XOR
      bf16x8 bv;
      #pragma unroll
      for (int j = 0; j < 8; ++j)
        bv[j] = Fb[(g4 * 8 + j) * CIN + pc * 8 + (c16 & 7)];
      f32x4 acc = __builtin_amdgcn_mfma_f32_16x16x32_bf16(a, bv, (f32x4){0.f, 0.f, 0.f, 0.f}, 0, 0, 0);
      #pragma unroll
      for (int r = 0; r < 4; ++r) {
        int p = g4 * 4 + r;
        if (p < 15) {
          int Lf = p * CPRow + Lc;
          int phys = (Lf & ~7) | ((Lf & 7) ^ (row & 7));
          s_fk[(size_t)row * KK + phys * 8 + (c16 & 7)] = (__bf16)acc[r];
        }
      }
    }
  };

  // publish s_q
  asm volatile("s_waitcnt lgkmcnt(0)" ::: "memory");
  __builtin_amdgcn_s_barrier();
  __builtin_amdgcn_sched_barrier(0);

  // ---- phase 1: pipelined agg; uniform G+1 vmem ops/iter across all waves ----
  float4 spc, spn;
  {
    stageF(0, idxg[0]);
    float4 sp0 = sp[idxi[0]];
    spc = sp[idxi[1 < NB ? 1 : 0]];
    float v0[4];
    inflC(sp0, 0, v0);
    inflStore(v0);
  }
  __builtin_amdgcn_sched_barrier(0);
  #pragma unroll
  for (int b = 0; b < NB; ++b) {
    if (b + 1 < NB) stageF((b + 1) & 1, idxg[b + 1]);
    if (b + 2 < NB) spn = sp[idxi[b + 2]];
    float vn[4];
    if (b + 1 < NB) inflC(spc, b + 1, vn);
    if (b == NB - 1)      { asm volatile("s_waitcnt vmcnt(0)" ::: "memory"); }
    else if (b == NB - 2) { if (G == 1) asm volatile("s_waitcnt vmcnt(1)" ::: "memory");
                            else        asm volatile("s_waitcnt vmcnt(2)" ::: "memory"); }
    else                  { if (G == 1) asm volatile("s_waitcnt vmcnt(2)" ::: "memory");
                            else        asm volatile("s_waitcnt vmcnt(3)" ::: "memory"); }
    asm volatile("s_waitcnt lgkmcnt(0)" ::: "memory");
    __builtin_amdgcn_s_barrier();
    __builtin_amdgcn_sched_barrier(0);
    mfmaBatch(b, b & 1);
    asm volatile("s_waitcnt lgkmcnt(0)" ::: "memory");
    __builtin_amdgcn_s_barrier();
    __builtin_amdgcn_sched_barrier(0);
    if (b + 1 < NB) { inflStore(vn); spc = spn; }
  }
  __syncthreads();

  // ---- phase 2: GEMM fk[BM][KK] x BT[COUT][KK]^T ----
  const int wr = w / CG, wc = w % CG;
  f32x4 acc[NJ];
  #pragma unroll
  for (int j = 0; j < NJ; ++j) acc[j] = (f32x4){0.f, 0.f, 0.f, 0.f};
  auto stageB = [&](int buf, int kt) {
    #pragma unroll
    for (int rnd = 0; rnd < COUT / 64; ++rnd) {
      int slot = rnd * 512 + t;
      int row = slot >> 3, bch = slot & 7;
      GLOAD_LDS16(BT + (size_t)row * KK + kt * 64 + (bch ^ (row & 7)) * 8,
                  s_B + buf * (COUT * 64) + slot * 8);
    }
  };
  const __bf16* fkrow = s_fk + (size_t)(wr * 16 + c16) * KK;
  auto computeTile = [&](int kt, int buf) {
    bf16x8 af[2];
    #pragma unroll
    for (int s = 0; s < 2; ++s)
      af[s] = *(const bf16x8*)&fkrow[(kt * 8 + ((s * 4 + g4) ^ (c16 & 7))) * 8];
    const __bf16* Bb = s_B + buf * (COUT * 64);
    #pragma unroll
    for (int j = 0; j < NJ; ++j) {
      int n = wc * (16 * NJ) + j * 16 + c16;
      #pragma unroll
      for (int s = 0; s < 2; ++s) {
        bf16x8 bf = *(const bf16x8*)&Bb[n * 64 + ((s * 4 + g4) ^ (n & 7)) * 8];
        acc[j] = __builtin_amdgcn_mfma_f32_16x16x32_bf16(af[s], bf, acc[j], 0, 0, 0);
      }
    }
  };
  if (BDBUF) {
    stageB(0, 0);
    __syncthreads();
    for (int kt = 0; kt < KT; ++kt) {
      if (kt + 1 < KT) stageB((kt + 1) & 1, kt + 1);
      computeTile(kt, kt & 1);
      __syncthreads();
    }
  } else {
    for (int kt = 0; kt < KT; ++kt) {
      stageB(0, kt);
      __syncthreads();
      computeTile(kt, 0);
      __syncthreads();
    }
  }
  // ---- epilogue ----
  #pragma unroll
  for (int j = 0; j < NJ; ++j)
    #pragma unroll
    for (int r = 0; r < 4; ++r) {
      int row = m0 + wr * 16 + g4 * 4 + r;
      int col = wc * (16 * NJ) + j * 16 + c16;
      if (row < M) {
        float v = acc[j][r];
        v = v > 0.f ? v : 0.1f * v;
        out[(size_t)row * COUT + col] = (__bf16)v;
      }
    }
}

// ---------------- MFMA bf16 GEMM (decoder D1): C[M,N] = Aeff[M,KK] * BT[N,KK]^T ----------------
template <bool LEAKY, bool GATHER>
__global__ __launch_bounds__(256, 2) void gemm_mfma(
    const __bf16* __restrict__ A1, const __bf16* __restrict__ A2,
    const int* __restrict__ gidx, const int K1,
    const __bf16* __restrict__ BT, __bf16* __restrict__ Cout,
    const int M, const int N, const int KK) {
  __shared__ __bf16 sA[2][4096];
  __shared__ __bf16 sB[2][4096];
  const int t = threadIdx.x;
  const int lane = t & 63, wave = t >> 6;
  const int wr = wave >> 1, wc = wave & 1;
  const int m0 = blockIdx.y * 64, n0 = blockIdx.x * 64;
  const int K2 = KK - K1;

  const __bf16* a1row[2];
  const __bf16* a2row[2];
  const __bf16* brow_[2];
  int csrc[2], wbase[2];
  #pragma unroll
  for (int r = 0; r < 2; ++r) {
    int slot = r * 256 + wave * 64 + lane;
    int row = slot >> 3;
    csrc[r] = ((slot & 7) ^ (row & 7)) * 8;
    wbase[r] = (r * 256 + wave * 64) * 8;
    int gm = m0 + row; if (gm > M - 1) gm = M - 1;
    if (GATHER) {
      a1row[r] = A1 + (size_t)gidx[gm] * K1;
      a2row[r] = A2 + (size_t)gm * (size_t)K2;
    } else {
      a1row[r] = A1 + (size_t)gm * (size_t)KK;
    }
    int gn = n0 + row; if (gn > N - 1) gn = N - 1;
    brow_[r] = BT + (size_t)gn * (size_t)KK;
  }

  int offA[2][2], offB[2][2];
  #pragma unroll
  for (int i = 0; i < 2; ++i)
    #pragma unroll
    for (int s = 0; s < 2; ++s) {
      int ra = wr * 32 + i * 16 + (lane & 15);
      int rb = wc * 32 + i * 16 + (lane & 15);
      int chn = s * 4 + (lane >> 4);
      offA[i][s] = ra * 64 + (chn ^ (ra & 7)) * 8;
      offB[i][s] = rb * 64 + (chn ^ (rb & 7)) * 8;
    }

  f32x4 acc[2][2];
  #pragma unroll
  for (int i = 0; i < 2; ++i)
    #pragma unroll
    for (int j = 0; j < 2; ++j) acc[i][j] = (f32x4){0.f, 0.f, 0.f, 0.f};

  auto stage = [&](int buf, int k0) {
    #pragma unroll
    for (int r = 0; r < 2; ++r) {
      int kg = k0 + csrc[r];
      const __bf16* asrc;
      if (GATHER) asrc = (kg < K1) ? (a1row[r] + kg) : (a2row[r] + (kg - K1));
      else        asrc = a1row[r] + kg;
      GLOAD_LDS16(asrc, &sA[buf][wbase[r]]);
      GLOAD_LDS16(brow_[r] + kg, &sB[buf][wbase[r]]);
    }
  };

  stage(0, 0);
  __syncthreads();
  const int nk = KK >> 6;
  int cur = 0;
  for (int kt = 0; kt < nk; ++kt) {
    if (kt + 1 < nk) stage(cur ^ 1, (kt + 1) << 6);
    #pragma unroll
    for (int s = 0; s < 2; ++s) {
      bf16x8 a0 = *(const bf16x8*)&sA[cur][offA[0][s]];
      bf16x8 a1 = *(const bf16x8*)&sA[cur][offA[1][s]];
      bf16x8 b0 = *(const bf16x8*)&sB[cur][offB[0][s]];
      bf16x8 b1 = *(const bf16x8*)&sB[cur][offB[1][s]];
      acc[0][0] = __builtin_amdgcn_mfma_f32_16x16x32_bf16(a0, b0, acc[0][0], 0, 0, 0);
      acc[0][1] = __builtin_amdgcn_mfma_f32_16x16x32_bf16(a0, b1, acc[0][1], 0, 0, 0);
      acc[1][0] = __builtin_amdgcn_mfma_f32_16x16x32_bf16(a1, b0, acc[1][0], 0, 0, 0);
      acc[1][1] = __builtin_amdgcn_mfma_f32_16x16x32_bf16(a1, b1, acc[1][1], 0, 0, 0);
    }
    __syncthreads();
    cur ^= 1;
  }

  #pragma unroll
  for (int i = 0; i < 2; ++i)
    #pragma unroll
    for (int j = 0; j < 2; ++j)
      #pragma unroll
      for (int g = 0; g < 4; ++g) {
        int row = m0 + wr * 32 + i * 16 + (lane >> 4) * 4 + g;
        int col = n0 + wc * 32 + j * 16 + (lane & 15);
        if (row < M && col < N) {
          float v = acc[i][j][g];
          if (LEAKY) v = v > 0.f ? v : 0.1f * v;
          Cout[(size_t)row * N + col] = (__bf16)v;
        }
      }
}

// ---------------- D2: f6[M,32] = concat(f5[up0], f0) @ Wu2, full-K LDS, fused gmax ----------------
// 128 rows x 32 cols per block; K=192 = 24 chunks/row, XOR-swizzled; 62KB LDS -> 2 blocks/CU.
__global__ __launch_bounds__(256) void d2_kernel(
    const __bf16* __restrict__ f5b, const __bf16* __restrict__ f0b,
    const int* __restrict__ up0, const __bf16* __restrict__ BT,
    float* __restrict__ f6, int M, unsigned* __restrict__ gmax) {
  __shared__ __bf16 sA[128 * 192];
  __shared__ __bf16 sB[32 * 192];
  __shared__ int s_g[128];
  __shared__ float s_max[4];
  const int t = threadIdx.x;
  const int m0 = blockIdx.x * 128;
  if (t < 128) { int m = m0 + t; s_g[t] = up0[m < M ? m : M - 1]; }
  __syncthreads();
  // stage B: 32 rows x 24 chunks = 768 slots
  #pragma unroll
  for (int rnd = 0; rnd < 3; ++rnd) {
    int slot = rnd * 256 + t;
    int row = slot / 24, chd = slot % 24;
    int chs = (chd & ~7) | ((chd & 7) ^ (row & 7));
    GLOAD_LDS16(BT + (size_t)row * 192 + chs * 8, sB + slot * 8);
  }
  // stage A: 128 rows x 24 chunks = 3072 slots; row = concat(f5[g], f0[m])
  #pragma unroll
  for (int rnd = 0; rnd < 12; ++rnd) {
    int slot = rnd * 256 + t;
    int row = slot / 24, chd = slot % 24;
    int chs = (chd & ~7) | ((chd & 7) ^ (row & 7));
    int m = m0 + row; if (m > M - 1) m = M - 1;
    const __bf16* src = (chs < 16) ? (f5b + (size_t)s_g[row] * 128 + chs * 8)
                                   : (f0b + (size_t)m * 64 + (chs - 16) * 8);
    GLOAD_LDS16(src, sA + slot * 8);
  }
  __syncthreads();
  const int w = t >> 6, lane = t & 63;
  const int c16 = lane & 15, g4 = lane >> 4;
  f32x4 acc[2][2];
  #pragma unroll
  for (int i = 0; i < 2; ++i)
    #pragma unroll
    for (int j = 0; j < 2; ++j) acc[i][j] = (f32x4){0.f, 0.f, 0.f, 0.f};
  #pragma unroll
  for (int ks = 0; ks < 6; ++ks) {
    bf16x8 a[2], b[2];
    #pragma unroll
    for (int i = 0; i < 2; ++i) {
      int row = w * 32 + i * 16 + c16;
      int chunk = ks * 4 + g4;
      int phys = (chunk & ~7) | ((chunk & 7) ^ (row & 7));
      a[i] = *(const bf16x8*)&sA[(row * 24 + phys) * 8];
    }
    #pragma unroll
    for (int j = 0; j < 2; ++j) {
      int n = j * 16 + c16;
      int chunk = ks * 4 + g4;
      int phys = (chunk & ~7) | ((chunk & 7) ^ (n & 7));
      b[j] = *(const bf16x8*)&sB[(n * 24 + phys) * 8];
    }
    #pragma unroll
    for (int i = 0; i < 2; ++i)
      #pragma unroll
      for (int j = 0; j < 2; ++j)
        acc[i][j] = __builtin_amdgcn_mfma_f32_16x16x32_bf16(a[i], b[j], acc[i][j], 0, 0, 0);
  }
  float lmax = 0.f;
  #pragma unroll
  for (int i = 0; i < 2; ++i)
    #pragma unroll
    for (int j = 0; j < 2; ++j)
      #pragma unroll
      for (int g = 0; g < 4; ++g) {
        int row = m0 + w * 32 + i * 16 + g4 * 4 + g;
        int col = j * 16 + c16;
        if (row < M) {
          float v = acc[i][j][g];
          lmax = fmaxf(lmax, v);
          f6[(size_t)row * 32 + col] = v;
        }
      }
  #pragma unroll
  for (int s = 32; s >= 1; s >>= 1) lmax = fmaxf(lmax, __shfl_xor(lmax, s, 64));
  if (lane == 0) s_max[w] = lmax;
  __syncthreads();
  if (t == 0) {
    float mm = fmaxf(fmaxf(s_max[0], s_max[1]), fmaxf(s_max[2], s_max[3]));
    atomicMax(gmax, __float_as_uint(mm));
  }
}

// ---------------- detection + fnorm; nnum==32 (neighbor row sums never exactly 0) ----------------
__global__ __launch_bounds__(256) void detect_kernel(
    const float* __restrict__ f6, const int* __restrict__ neigh,
    const float* __restrict__ gm_ptr, float* __restrict__ out_fnorm,
    float* __restrict__ out_scores, int N) {
  int n = blockIdx.x * 8 + (threadIdx.x >> 5);
  int c = threadIdx.x & 31;
  if (n >= N) return;
  float denom = gm_ptr[0] + 1e-6f;
  float fown = f6[(size_t)n * 32 + c];
  int idx_l = neigh[(size_t)n * 32 + c];
  float colsum = 0.f, colmax = -1e30f;
  for (int k = 0; k < 32; ++k) {
    int idx = __shfl(idx_l, k, 32);
    float v = f6[(size_t)idx * 32 + c];
    colsum += v;
    colmax = fmaxf(colmax, v);
  }
  float fs = fown / denom;
  float mean = (colsum / denom) * (1.f / 32.f);
  float x = fs - mean;
  float lms = fmaxf(x, 0.f) + log1pf(expf(-fabsf(x)));  // softplus
  float dm = fs;
  #pragma unroll
  for (int s = 16; s >= 1; s >>= 1) dm = fmaxf(dm, __shfl_xor(dm, s, 32));
  float as = lms * fs / (1e-6f + dm);
  float sc = as;
  #pragma unroll
  for (int s = 16; s >= 1; s >>= 1) sc = fmaxf(sc, __shfl_xor(sc, s, 32));
  float det = (fown == colmax) ? 1.f : 0.f;
  #pragma unroll
  for (int s = 16; s >= 1; s >>= 1) det = fmaxf(det, __shfl_xor(det, s, 32));
  float nn2 = fown * fown;
  #pragma unroll
  for (int s = 16; s >= 1; s >>= 1) nn2 += __shfl_xor(nn2, s, 32);
  float inv_nrm = 1.f / fmaxf(sqrtf(nn2), 1e-12f);
  out_fnorm[(size_t)n * 32 + c] = fown * inv_nrm;
  if (c == 0) out_scores[n] = sc * det;
}

extern "C" void kernel_launch(void* const* d_in, const int* in_sizes, int n_in,
                              void* d_out, int out_size, void* d_ws, size_t ws_size,
                              hipStream_t stream) {
  const float* features  = (const float*)d_in[0];
  const float* points0   = (const float*)d_in[1];
  const float* points1   = (const float*)d_in[2];
  const float* points2   = (const float*)d_in[3];
  const int* neighbors0  = (const int*)d_in[4];
  const int* neighbors1  = (const int*)d_in[5];
  const int* neighbors2  = (const int*)d_in[6];
  const int* pools0      = (const int*)d_in[7];
  const int* pools1      = (const int*)d_in[8];
  const int* upsamples0  = (const int*)d_in[9];
  const int* upsamples1  = (const int*)d_in[10];
  const float* kpoints   = (const float*)d_in[11];
  const float* W1  = (const float*)d_in[12];
  const float* W2  = (const float*)d_in[13];
  const float* W3  = (const float*)d_in[14];
  const float* W4  = (const float*)d_in[15];
  const float* W5  = (const float*)d_in[16];
  const float* Wu1 = (const float*)d_in[17];
  const float* Wu2 = (const float*)d_in[18];

  const float R0 = 0.5f;

  char* wp = (char*)d_ws;
  auto alloc = [&](size_t bytes) {
    char* r = wp;
    wp += (bytes + 255) & ~(size_t)255;
    return r;
  };
  __bf16* f0b  = (__bf16*)alloc((size_t)cN0 * 64 * 2);
  __bf16* f1b  = (__bf16*)alloc((size_t)cN1 * 64 * 2);
  __bf16* f2b  = (__bf16*)alloc((size_t)cN1 * 128 * 2);
  __bf16* f3b  = (__bf16*)alloc((size_t)cN2 * 128 * 2);
  __bf16* f4b  = (__bf16*)alloc((size_t)cN2 * 256 * 2);
  __bf16* f5b  = (__bf16*)alloc((size_t)cN1 * 128 * 2);
  float*  f6   = (float*)alloc((size_t)cN0 * 32 * 4);
  __bf16* WT2  = (__bf16*)alloc(960 * 64 * 2);
  __bf16* WT3  = (__bf16*)alloc(960 * 128 * 2);
  __bf16* WT4  = (__bf16*)alloc(1920 * 128 * 2);
  __bf16* WT5  = (__bf16*)alloc(1920 * 256 * 2);
  __bf16* WTu1 = (__bf16*)alloc(384 * 128 * 2);
  __bf16* WTu2 = (__bf16*)alloc(192 * 32 * 2);
  unsigned* gm = (unsigned*)alloc(256);
  float4* pk0  = (float4*)alloc((size_t)cN0 * 16);
  float4* pk1  = (float4*)alloc((size_t)cN1 * 16);
  float4* pk2  = (float4*)alloc((size_t)cN2 * 16);

  prep_kernel<<<dim3(240, 9), 256, 0, stream>>>(
      points0, features, points1, points2, W2, W3, W4, W5, Wu1, Wu2,
      pk0, pk1, pk2, WT2, WT3, WT4, WT5, WTu1, WTu2);
  kpconv_l1<<<cN0 / 16, 256, 0, stream>>>(pk0, neighbors0, kpoints, W1, f0b, R0);

  // L2: strided, f0 -> f1 [N1,64]   (BM=32, 2 blocks/CU, 469 blocks)
  kpconv_fused<64, 64, 32, true><<<(cN1 + 31) / 32, 512, 0, stream>>>(
      pk1, pk0, pools0, f0b, kpoints, WT2, f1b, cN1, R0);
  // L3: simple, f1 -> f2 [N1,128]
  kpconv_fused<64, 128, 32, false><<<(cN1 + 31) / 32, 512, 0, stream>>>(
      pk1, pk1, neighbors1, f1b, kpoints, WT3, f2b, cN1, 2.f * R0);
  // L4: strided, f2 -> f3 [N2,128]
  kpconv_fused<128, 128, 16, true><<<(cN2 + 15) / 16, 512, 0, stream>>>(
      pk2, pk1, pools1, f2b, kpoints, WT4, f3b, cN2, 2.f * R0);
  // L5: simple, f3 -> f4 [N2,256]
  kpconv_fused<128, 256, 16, false><<<(cN2 + 15) / 16, 512, 0, stream>>>(
      pk2, pk2, neighbors2, f3b, kpoints, WT5, f4b, cN2, 4.f * R0);

  // D1: f5 = leaky(concat(f4[up1], f2) @ Wu1)
  gemm_mfma<true, true><<<dim3(2, 235), 256, 0, stream>>>(
      f4b, f2b, upsamples1, 256, WTu1, f5b, cN1, 128, 384);
  // D2: f6 = concat(f5[up0], f0) @ Wu2  (f32 out, fused global max)
  hipMemsetAsync(gm, 0, 4, stream);
  d2_kernel<<<(cN0 + 127) / 128, 256, 0, stream>>>(
      f5b, f0b, upsamples0, WTu2, f6, cN0, gm);

  float* out_fnorm = (float*)d_out;
  float* out_scores = out_fnorm + (size_t)cN0 * 32;
  detect_kernel<<<(cN0 + 7) / 8, 256, 0, stream>>>(f6, neighbors0, (const float*)gm,
                                                   out_fnorm, out_scores, cN0);
}

// Round 9
// 202.980 us; speedup vs baseline: 4.4102x; 1.0103x over previous
//
#include <hip/hip_runtime.h>
#include <math.h>

static const int cN0 = 60000;
static const int cN1 = 15000;
static const int cN2 = 3750;

typedef __bf16 bf16x8 __attribute__((ext_vector_type(8)));
typedef float f32x4 __attribute__((ext_vector_type(4)));

#define GLOAD_LDS16(gsrc, ldst)                                                        \
  __builtin_amdgcn_global_load_lds((const __attribute__((address_space(1))) void*)(gsrc), \
                                   (__attribute__((address_space(3))) void*)(ldst), 16, 0, 0)

// ---------------- prep: pack points(+feat) into float4; transpose weights; zero gmax ----------------
__global__ __launch_bounds__(256) void prep_kernel(
    const float* __restrict__ pts0, const float* __restrict__ feat,
    const float* __restrict__ pts1, const float* __restrict__ pts2,
    const float* __restrict__ W2, const float* __restrict__ W3, const float* __restrict__ W4,
    const float* __restrict__ W5, const float* __restrict__ Wu1, const float* __restrict__ Wu2,
    float4* __restrict__ pk0, float4* __restrict__ pk1, float4* __restrict__ pk2,
    __bf16* __restrict__ T2, __bf16* __restrict__ T3, __bf16* __restrict__ T4,
    __bf16* __restrict__ T5, __bf16* __restrict__ Tu1, __bf16* __restrict__ Tu2,
    unsigned* __restrict__ gm) {
  int role = blockIdx.y;
  int tid = blockIdx.x * 256 + threadIdx.x;
  int stride = gridDim.x * 256;
  if (role == 0 && tid == 0) gm[0] = 0u;
  if (role < 3) {
    const float* p = role == 0 ? pts0 : (role == 1 ? pts1 : pts2);
    float4* o = role == 0 ? pk0 : (role == 1 ? pk1 : pk2);
    int n = role == 0 ? cN0 : (role == 1 ? cN1 : cN2);
    for (int i = tid; i < n; i += stride) {
      float4 v;
      v.x = p[(size_t)i * 3 + 0];
      v.y = p[(size_t)i * 3 + 1];
      v.z = p[(size_t)i * 3 + 2];
      v.w = role == 0 ? feat[i] : 0.f;
      o[i] = v;
    }
  } else {
    const float* src;
    __bf16* dst;
    int Kd, Nd;
    switch (role) {
      case 3: src = W2;  dst = T2;  Kd = 960;  Nd = 64;  break;
      case 4: src = W3;  dst = T3;  Kd = 960;  Nd = 128; break;
      case 5: src = W4;  dst = T4;  Kd = 1920; Nd = 128; break;
      case 6: src = W5;  dst = T5;  Kd = 1920; Nd = 256; break;
      case 7: src = Wu1; dst = Tu1; Kd = 384;  Nd = 128; break;
      default: src = Wu2; dst = Tu2; Kd = 192; Nd = 32;  break;
    }
    int total = Kd * Nd;
    for (int e = tid; e < total; e += stride) {
      int n = e / Kd, k = e % Kd;
      dst[e] = (__bf16)src[(size_t)k * Nd + n];
    }
  }
}

// ---------------- L1 kpconv: Cin=1 -> 64, 32 points/block (512 thr), packed float4 gather -------
__global__ __launch_bounds__(512) void kpconv_l1(
    const float4* __restrict__ pk, const int* __restrict__ neigh,
    const float* __restrict__ kpts, const float* __restrict__ W1,
    __bf16* __restrict__ f0, float extent) {
  const int t = threadIdx.x;
  const int n0b = blockIdx.x * 32;
  __shared__ float s_nb[32][32][4];   // [k][pt][xyzf]
  __shared__ float s_fk[32][16];      // [pt][p]
  __shared__ float s_W[960];
  for (int i = t; i < 960; i += 512) s_W[i] = W1[i];
  #pragma unroll
  for (int i = 0; i < 2; ++i) {
    int e = t + i * 512;
    int pt = e & 31, k = e >> 5;
    int idx = neigh[(size_t)(n0b + pt) * 32 + k];
    *(float4*)&s_nb[k][pt][0] = pk[idx];
  }
  __syncthreads();
  const int lane = t & 63, wave = t >> 6;
  const int g = lane >> 4, p_raw = lane & 15;
  const int p = p_raw < 15 ? p_raw : 0;
  const int pt = wave * 4 + g;
  const int n = n0b + pt;
  const float inv = 1.f / extent;
  float4 q = pk[n];
  const float kx = q.x + kpts[p * 3 + 0] * extent;
  const float ky = q.y + kpts[p * 3 + 1] * extent;
  const float kz = q.z + kpts[p * 3 + 2] * extent;
  float fk = 0.f;
  #pragma unroll 8
  for (int k = 0; k < 32; ++k) {
    f32x4 rec = *(const f32x4*)&s_nb[k][pt][0];
    float dx = rec[0] - kx, dy = rec[1] - ky, dz = rec[2] - kz;
    float d = sqrtf(dx * dx + dy * dy + dz * dz);
    fk += fmaxf(0.f, 1.f - d * inv) * rec[3];
  }
  if (p_raw < 15) s_fk[pt][p_raw] = fk;
  __syncthreads();
  #pragma unroll
  for (int o = 0; o < 4; ++o) {
    int e = o * 512 + t;
    int opt = e >> 6, c = e & 63;
    float acc = 0.f;
    #pragma unroll
    for (int pp = 0; pp < 15; ++pp) acc += s_fk[opt][pp] * s_W[pp * 64 + c];
    acc = acc > 0.f ? acc : 0.1f * acc;
    f0[(size_t)(n0b + opt) * 64 + c] = (__bf16)acc;
  }
}

// ---------------- FUSED kpconv layer: agg (LDS fk) + GEMM ----------------
template <int CIN, int COUT, int BM, bool BDBUF>
__global__ __launch_bounds__(512) void kpconv_fused(
    const float4* __restrict__ qp, const float4* __restrict__ sp,
    const int* __restrict__ neigh, const __bf16* __restrict__ F,
    const float* __restrict__ kpts, const __bf16* __restrict__ BT,
    __bf16* __restrict__ out, int M, float extent) {
  constexpr int KK = 15 * CIN;
  constexpr int KT = KK / 64;
  constexpr int CPRow = CIN / 8;
  constexpr int G = CIN / 64;
  constexpr int GS = 64 / G;
  constexpr int NB = BM / 2;
  constexpr int CPW = CIN / 64;
  constexpr int FBUF = 64 * CIN;
  constexpr int RG = BM / 16;
  constexpr int CG = 8 / RG;
  constexpr int NJ = COUT / (16 * CG);
  constexpr int SMEM_FK = BM * KK * 2;
  constexpr int SMEM = SMEM_FK + 2 * 1280 + BM * 16 + 2 * FBUF * 2;

  __shared__ __align__(16) char smem[SMEM];
  __bf16* s_fk   = (__bf16*)smem;
  __bf16* s_infl = (__bf16*)(smem + SMEM_FK);
  float4* s_q    = (float4*)(smem + SMEM_FK + 2 * 1280);
  __bf16* s_F    = (__bf16*)(smem + SMEM_FK + 2 * 1280 + BM * 16);
  __bf16* s_B    = s_F;

  const int t = threadIdx.x;
  const int w = t >> 6, l = t & 63;
  const int c16 = l & 15, g4 = l >> 4;
  const int m0 = blockIdx.x * BM;
  const int* nb_base = neigh + (size_t)m0 * 32;
  int rlim = (M - m0) * 32 - 1;
  if (rlim > BM * 32 - 1) rlim = BM * 32 - 1;

  const int gb = t / CPRow;
  const int ch = t % CPRow;
  int idxg[NB][G];
  #pragma unroll
  for (int b = 0; b < NB; ++b)
    #pragma unroll
    for (int j = 0; j < G; ++j) {
      int r = b * 64 + gb + j * GS;
      idxg[b][j] = nb_base[r < rlim ? r : rlim];
    }
  const int row_i = (t >> 2) & 63;
  const int pq4 = (t & 3) * 4;
  const int pt_i = row_i >> 5, kk_i = row_i & 31;
  int idxi[NB];
  #pragma unroll
  for (int b = 0; b < NB; ++b) {
    int r = b * 64 + row_i;
    idxi[b] = nb_base[r < rlim ? r : rlim];
  }
  const float inv = 1.f / extent;
  float kpx[4], kpy[4], kpz[4];
  #pragma unroll
  for (int pi = 0; pi < 4; ++pi) {
    int p = pq4 + pi; if (p > 14) p = 14;
    kpx[pi] = kpts[p * 3 + 0] * extent;
    kpy[pi] = kpts[p * 3 + 1] * extent;
    kpz[pi] = kpts[p * 3 + 2] * extent;
  }
  if (t < BM) { int n = m0 + t; s_q[t] = qp[n < M ? n : M - 1]; }

  auto stageF = [&](int buf, const int (&ig)[G]) {
    #pragma unroll
    for (int j = 0; j < G; ++j) {
      int k = (gb + j * GS) & 31;
      const __bf16* src = F + (size_t)ig[j] * CIN + (ch ^ ((k >> 3) & 3)) * 8;
      GLOAD_LDS16(src, s_F + buf * FBUF + (j * 512 + t) * 8);
    }
  };
  auto inflC = [&](const float4& spv, int b, float (&v)[4]) {
    float4 q = s_q[b * 2 + pt_i];
    float sx = spv.x - q.x, sy = spv.y - q.y, sz = spv.z - q.z;
    #pragma unroll
    for (int pi = 0; pi < 4; ++pi) {
      float dx = sx - kpx[pi], dy = sy - kpy[pi], dz = sz - kpz[pi];
      float d = sqrtf(dx * dx + dy * dy + dz * dz);
      v[pi] = fmaxf(0.f, 1.f - d * inv);
    }
  };
  auto inflStore = [&](const float (&v)[4]) {
    if (t < 256) {
      #pragma unroll
      for (int pi = 0; pi < 4; ++pi) {
        int p = pq4 + pi;
        if (p < 15) s_infl[pt_i * 640 + p * 40 + kk_i] = (__bf16)v[pi];
      }
    }
  };
  auto mfmaBatch = [&](int b, int buf) {
    const int pt_loc = w / 4;
    const int cc0 = (w & 3) * CPW;
    const __bf16* Fb = s_F + buf * FBUF + pt_loc * (32 * CIN);
    bf16x8 a = *(const bf16x8*)&s_infl[pt_loc * 640 + c16 * 40 + g4 * 8];
    const int row = b * 2 + pt_loc;
    #pragma unroll
    for (int ci = 0; ci < CPW; ++ci) {
      const int cc = cc0 + ci;
      const int Lc = cc * 2 + (c16 >> 3);
      const int pc = Lc ^ g4;
      bf16x8 bv;
      #pragma unroll
      for (int j = 0; j < 8; ++j)
        bv[j] = Fb[(g4 * 8 + j) * CIN + pc * 8 + (c16 & 7)];
      f32x4 acc = __builtin_amdgcn_mfma_f32_16x16x32_bf16(a, bv, (f32x4){0.f, 0.f, 0.f, 0.f}, 0, 0, 0);
      #pragma unroll
      for (int r = 0; r < 4; ++r) {
        int p = g4 * 4 + r;
        if (p < 15) {
          int Lf = p * CPRow + Lc;
          int phys = (Lf & ~7) | ((Lf & 7) ^ (row & 7));
          s_fk[(size_t)row * KK + phys * 8 + (c16 & 7)] = (__bf16)acc[r];
        }
      }
    }
  };

  asm volatile("s_waitcnt lgkmcnt(0)" ::: "memory");
  __builtin_amdgcn_s_barrier();
  __builtin_amdgcn_sched_barrier(0);

  float4 spc, spn;
  {
    stageF(0, idxg[0]);
    float4 sp0 = sp[idxi[0]];
    spc = sp[idxi[1 < NB ? 1 : 0]];
    float v0[4];
    inflC(sp0, 0, v0);
    inflStore(v0);
  }
  __builtin_amdgcn_sched_barrier(0);
  #pragma unroll
  for (int b = 0; b < NB; ++b) {
    if (b + 1 < NB) stageF((b + 1) & 1, idxg[b + 1]);
    if (b + 2 < NB) spn = sp[idxi[b + 2]];
    float vn[4];
    if (b + 1 < NB) inflC(spc, b + 1, vn);
    if (b == NB - 1)      { asm volatile("s_waitcnt vmcnt(0)" ::: "memory"); }
    else if (b == NB - 2) { if (G == 1) asm volatile("s_waitcnt vmcnt(1)" ::: "memory");
                            else        asm volatile("s_waitcnt vmcnt(2)" ::: "memory"); }
    else                  { if (G == 1) asm volatile("s_waitcnt vmcnt(2)" ::: "memory");
                            else        asm volatile("s_waitcnt vmcnt(3)" ::: "memory"); }
    asm volatile("s_waitcnt lgkmcnt(0)" ::: "memory");
    __builtin_amdgcn_s_barrier();
    __builtin_amdgcn_sched_barrier(0);
    mfmaBatch(b, b & 1);
    asm volatile("s_waitcnt lgkmcnt(0)" ::: "memory");
    __builtin_amdgcn_s_barrier();
    __builtin_amdgcn_sched_barrier(0);
    if (b + 1 < NB) { inflStore(vn); spc = spn; }
  }
  __syncthreads();

  const int wr = w / CG, wc = w % CG;
  f32x4 acc[NJ];
  #pragma unroll
  for (int j = 0; j < NJ; ++j) acc[j] = (f32x4){0.f, 0.f, 0.f, 0.f};
  auto stageB = [&](int buf, int kt) {
    #pragma unroll
    for (int rnd = 0; rnd < COUT / 64; ++rnd) {
      int slot = rnd * 512 + t;
      int row = slot >> 3, bch = slot & 7;
      GLOAD_LDS16(BT + (size_t)row * KK + kt * 64 + (bch ^ (row & 7)) * 8,
                  s_B + buf * (COUT * 64) + slot * 8);
    }
  };
  const __bf16* fkrow = s_fk + (size_t)(wr * 16 + c16) * KK;
  auto computeTile = [&](int kt, int buf) {
    bf16x8 af[2];
    #pragma unroll
    for (int s = 0; s < 2; ++s)
      af[s] = *(const bf16x8*)&fkrow[(kt * 8 + ((s * 4 + g4) ^ (c16 & 7))) * 8];
    const __bf16* Bb = s_B + buf * (COUT * 64);
    #pragma unroll
    for (int j = 0; j < NJ; ++j) {
      int n = wc * (16 * NJ) + j * 16 + c16;
      #pragma unroll
      for (int s = 0; s < 2; ++s) {
        bf16x8 bf = *(const bf16x8*)&Bb[n * 64 + ((s * 4 + g4) ^ (n & 7)) * 8];
        acc[j] = __builtin_amdgcn_mfma_f32_16x16x32_bf16(af[s], bf, acc[j], 0, 0, 0);
      }
    }
  };
  if (BDBUF) {
    stageB(0, 0);
    __syncthreads();
    for (int kt = 0; kt < KT; ++kt) {
      if (kt + 1 < KT) stageB((kt + 1) & 1, kt + 1);
      computeTile(kt, kt & 1);
      __syncthreads();
    }
  } else {
    for (int kt = 0; kt < KT; ++kt) {
      stageB(0, kt);
      __syncthreads();
      computeTile(kt, 0);
      __syncthreads();
    }
  }
  #pragma unroll
  for (int j = 0; j < NJ; ++j)
    #pragma unroll
    for (int r = 0; r < 4; ++r) {
      int row = m0 + wr * 16 + g4 * 4 + r;
      int col = wc * (16 * NJ) + j * 16 + c16;
      if (row < M) {
        float v = acc[j][r];
        v = v > 0.f ? v : 0.1f * v;
        out[(size_t)row * COUT + col] = (__bf16)v;
      }
    }
}

// ---------------- MFMA bf16 GEMM (decoder D1) ----------------
template <bool LEAKY, bool GATHER>
__global__ __launch_bounds__(256, 2) void gemm_mfma(
    const __bf16* __restrict__ A1, const __bf16* __restrict__ A2,
    const int* __restrict__ gidx, const int K1,
    const __bf16* __restrict__ BT, __bf16* __restrict__ Cout,
    const int M, const int N, const int KK) {
  __shared__ __bf16 sA[2][4096];
  __shared__ __bf16 sB[2][4096];
  const int t = threadIdx.x;
  const int lane = t & 63, wave = t >> 6;
  const int wr = wave >> 1, wc = wave & 1;
  const int m0 = blockIdx.y * 64, n0 = blockIdx.x * 64;
  const int K2 = KK - K1;

  const __bf16* a1row[2];
  const __bf16* a2row[2];
  const __bf16* brow_[2];
  int csrc[2], wbase[2];
  #pragma unroll
  for (int r = 0; r < 2; ++r) {
    int slot = r * 256 + wave * 64 + lane;
    int row = slot >> 3;
    csrc[r] = ((slot & 7) ^ (row & 7)) * 8;
    wbase[r] = (r * 256 + wave * 64) * 8;
    int gm = m0 + row; if (gm > M - 1) gm = M - 1;
    if (GATHER) {
      a1row[r] = A1 + (size_t)gidx[gm] * K1;
      a2row[r] = A2 + (size_t)gm * (size_t)K2;
    } else {
      a1row[r] = A1 + (size_t)gm * (size_t)KK;
    }
    int gn = n0 + row; if (gn > N - 1) gn = N - 1;
    brow_[r] = BT + (size_t)gn * (size_t)KK;
  }

  int offA[2][2], offB[2][2];
  #pragma unroll
  for (int i = 0; i < 2; ++i)
    #pragma unroll
    for (int s = 0; s < 2; ++s) {
      int ra = wr * 32 + i * 16 + (lane & 15);
      int rb = wc * 32 + i * 16 + (lane & 15);
      int chn = s * 4 + (lane >> 4);
      offA[i][s] = ra * 64 + (chn ^ (ra & 7)) * 8;
      offB[i][s] = rb * 64 + (chn ^ (rb & 7)) * 8;
    }

  f32x4 acc[2][2];
  #pragma unroll
  for (int i = 0; i < 2; ++i)
    #pragma unroll
    for (int j = 0; j < 2; ++j) acc[i][j] = (f32x4){0.f, 0.f, 0.f, 0.f};

  auto stage = [&](int buf, int k0) {
    #pragma unroll
    for (int r = 0; r < 2; ++r) {
      int kg = k0 + csrc[r];
      const __bf16* asrc;
      if (GATHER) asrc = (kg < K1) ? (a1row[r] + kg) : (a2row[r] + (kg - K1));
      else        asrc = a1row[r] + kg;
      GLOAD_LDS16(asrc, &sA[buf][wbase[r]]);
      GLOAD_LDS16(brow_[r] + kg, &sB[buf][wbase[r]]);
    }
  };

  stage(0, 0);
  __syncthreads();
  const int nk = KK >> 6;
  int cur = 0;
  for (int kt = 0; kt < nk; ++kt) {
    if (kt + 1 < nk) stage(cur ^ 1, (kt + 1) << 6);
    #pragma unroll
    for (int s = 0; s < 2; ++s) {
      bf16x8 a0 = *(const bf16x8*)&sA[cur][offA[0][s]];
      bf16x8 a1 = *(const bf16x8*)&sA[cur][offA[1][s]];
      bf16x8 b0 = *(const bf16x8*)&sB[cur][offB[0][s]];
      bf16x8 b1 = *(const bf16x8*)&sB[cur][offB[1][s]];
      acc[0][0] = __builtin_amdgcn_mfma_f32_16x16x32_bf16(a0, b0, acc[0][0], 0, 0, 0);
      acc[0][1] = __builtin_amdgcn_mfma_f32_16x16x32_bf16(a0, b1, acc[0][1], 0, 0, 0);
      acc[1][0] = __builtin_amdgcn_mfma_f32_16x16x32_bf16(a1, b0, acc[1][0], 0, 0, 0);
      acc[1][1] = __builtin_amdgcn_mfma_f32_16x16x32_bf16(a1, b1, acc[1][1], 0, 0, 0);
    }
    __syncthreads();
    cur ^= 1;
  }

  #pragma unroll
  for (int i = 0; i < 2; ++i)
    #pragma unroll
    for (int j = 0; j < 2; ++j)
      #pragma unroll
      for (int g = 0; g < 4; ++g) {
        int row = m0 + wr * 32 + i * 16 + (lane >> 4) * 4 + g;
        int col = n0 + wc * 32 + j * 16 + (lane & 15);
        if (row < M && col < N) {
          float v = acc[i][j][g];
          if (LEAKY) v = v > 0.f ? v : 0.1f * v;
          Cout[(size_t)row * N + col] = (__bf16)v;
        }
      }
}

// ---------------- D2: f6[M,32] (f32) = concat(f5[up0], f0) @ Wu2, fused gmax ----------------
// f6 MUST stay f32: detection's (fown == colmax) equality test is discontinuous;
// bf16 rounding creates spurious ties (Round-8 failure: scores absmax 0.87).
__global__ __launch_bounds__(256) void d2_kernel(
    const __bf16* __restrict__ f5b, const __bf16* __restrict__ f0b,
    const int* __restrict__ up0, const __bf16* __restrict__ BT,
    float* __restrict__ f6, int M, unsigned* __restrict__ gmax) {
  __shared__ __bf16 sA[128 * 192];
  __shared__ __bf16 sB[32 * 192];
  __shared__ int s_g[128];
  __shared__ float s_max[4];
  const int t = threadIdx.x;
  const int m0 = blockIdx.x * 128;
  if (t < 128) { int m = m0 + t; s_g[t] = up0[m < M ? m : M - 1]; }
  __syncthreads();
  #pragma unroll
  for (int rnd = 0; rnd < 3; ++rnd) {
    int slot = rnd * 256 + t;
    int row = slot / 24, chd = slot % 24;
    int chs = (chd & ~7) | ((chd & 7) ^ (row & 7));
    GLOAD_LDS16(BT + (size_t)row * 192 + chs * 8, sB + slot * 8);
  }
  #pragma unroll
  for (int rnd = 0; rnd < 12; ++rnd) {
    int slot = rnd * 256 + t;
    int row = slot / 24, chd = slot % 24;
    int chs = (chd & ~7) | ((chd & 7) ^ (row & 7));
    int m = m0 + row; if (m > M - 1) m = M - 1;
    const __bf16* src = (chs < 16) ? (f5b + (size_t)s_g[row] * 128 + chs * 8)
                                   : (f0b + (size_t)m * 64 + (chs - 16) * 8);
    GLOAD_LDS16(src, sA + slot * 8);
  }
  __syncthreads();
  const int w = t >> 6, lane = t & 63;
  const int c16 = lane & 15, g4 = lane >> 4;
  f32x4 acc[2][2];
  #pragma unroll
  for (int i = 0; i < 2; ++i)
    #pragma unroll
    for (int j = 0; j < 2; ++j) acc[i][j] = (f32x4){0.f, 0.f, 0.f, 0.f};
  #pragma unroll
  for (int ks = 0; ks < 6; ++ks) {
    bf16x8 a[2], b[2];
    #pragma unroll
    for (int i = 0; i < 2; ++i) {
      int row = w * 32 + i * 16 + c16;
      int chunk = ks * 4 + g4;
      int phys = (chunk & ~7) | ((chunk & 7) ^ (row & 7));
      a[i] = *(const bf16x8*)&sA[(row * 24 + phys) * 8];
    }
    #pragma unroll
    for (int j = 0; j < 2; ++j) {
      int n = j * 16 + c16;
      int chunk = ks * 4 + g4;
      int phys = (chunk & ~7) | ((chunk & 7) ^ (n & 7));
      b[j] = *(const bf16x8*)&sB[(n * 24 + phys) * 8];
    }
    #pragma unroll
    for (int i = 0; i < 2; ++i)
      #pragma unroll
      for (int j = 0; j < 2; ++j)
        acc[i][j] = __builtin_amdgcn_mfma_f32_16x16x32_bf16(a[i], b[j], acc[i][j], 0, 0, 0);
  }
  float lmax = 0.f;
  #pragma unroll
  for (int i = 0; i < 2; ++i)
    #pragma unroll
    for (int j = 0; j < 2; ++j)
      #pragma unroll
      for (int g = 0; g < 4; ++g) {
        int row = m0 + w * 32 + i * 16 + g4 * 4 + g;
        int col = j * 16 + c16;
        if (row < M) {
          float v = acc[i][j][g];
          lmax = fmaxf(lmax, v);
          f6[(size_t)row * 32 + col] = v;
        }
      }
  #pragma unroll
  for (int s = 32; s >= 1; s >>= 1) lmax = fmaxf(lmax, __shfl_xor(lmax, s, 64));
  if (lane == 0) s_max[w] = lmax;
  __syncthreads();
  if (t == 0) {
    float mm = fmaxf(fmaxf(s_max[0], s_max[1]), fmaxf(s_max[2], s_max[3]));
    atomicMax(gmax, __float_as_uint(mm));
  }
}

// ---------------- detection + fnorm from f32 f6; 16 points/block (512 thr) ----------------
__global__ __launch_bounds__(512) void detect_kernel(
    const float* __restrict__ f6, const int* __restrict__ neigh,
    const float* __restrict__ gm_ptr, float* __restrict__ out_fnorm,
    float* __restrict__ out_scores, int N) {
  int n = blockIdx.x * 16 + (threadIdx.x >> 5);
  int c = threadIdx.x & 31;
  if (n >= N) return;
  float denom = gm_ptr[0] + 1e-6f;
  float fown = f6[(size_t)n * 32 + c];
  int idx_l = neigh[(size_t)n * 32 + c];
  float colsum = 0.f, colmax = -1e30f;
  for (int k = 0; k < 32; ++k) {
    int idx = __shfl(idx_l, k, 32);
    float v = f6[(size_t)idx * 32 + c];
    colsum += v;
    colmax = fmaxf(colmax, v);
  }
  float fs = fown / denom;
  float mean = (colsum / denom) * (1.f / 32.f);
  float x = fs - mean;
  float lms = fmaxf(x, 0.f) + log1pf(expf(-fabsf(x)));  // softplus
  float dm = fs;
  #pragma unroll
  for (int s = 16; s >= 1; s >>= 1) dm = fmaxf(dm, __shfl_xor(dm, s, 32));
  float as = lms * fs / (1e-6f + dm);
  float sc = as;
  #pragma unroll
  for (int s = 16; s >= 1; s >>= 1) sc = fmaxf(sc, __shfl_xor(sc, s, 32));
  float det = (fown == colmax) ? 1.f : 0.f;
  #pragma unroll
  for (int s = 16; s >= 1; s >>= 1) det = fmaxf(det, __shfl_xor(det, s, 32));
  float nn2 = fown * fown;
  #pragma unroll
  for (int s = 16; s >= 1; s >>= 1) nn2 += __shfl_xor(nn2, s, 32);
  float inv_nrm = 1.f / fmaxf(sqrtf(nn2), 1e-12f);
  out_fnorm[(size_t)n * 32 + c] = fown * inv_nrm;
  if (c == 0) out_scores[n] = sc * det;
}

extern "C" void kernel_launch(void* const* d_in, const int* in_sizes, int n_in,
                              void* d_out, int out_size, void* d_ws, size_t ws_size,
                              hipStream_t stream) {
  const float* features  = (const float*)d_in[0];
  const float* points0   = (const float*)d_in[1];
  const float* points1   = (const float*)d_in[2];
  const float* points2   = (const float*)d_in[3];
  const int* neighbors0  = (const int*)d_in[4];
  const int* neighbors1  = (const int*)d_in[5];
  const int* neighbors2  = (const int*)d_in[6];
  const int* pools0      = (const int*)d_in[7];
  const int* pools1      = (const int*)d_in[8];
  const int* upsamples0  = (const int*)d_in[9];
  const int* upsamples1  = (const int*)d_in[10];
  const float* kpoints   = (const float*)d_in[11];
  const float* W1  = (const float*)d_in[12];
  const float* W2  = (const float*)d_in[13];
  const float* W3  = (const float*)d_in[14];
  const float* W4  = (const float*)d_in[15];
  const float* W5  = (const float*)d_in[16];
  const float* Wu1 = (const float*)d_in[17];
  const float* Wu2 = (const float*)d_in[18];

  const float R0 = 0.5f;

  char* wp = (char*)d_ws;
  auto alloc = [&](size_t bytes) {
    char* r = wp;
    wp += (bytes + 255) & ~(size_t)255;
    return r;
  };
  __bf16* f0b  = (__bf16*)alloc((size_t)cN0 * 64 * 2);
  __bf16* f1b  = (__bf16*)alloc((size_t)cN1 * 64 * 2);
  __bf16* f2b  = (__bf16*)alloc((size_t)cN1 * 128 * 2);
  __bf16* f3b  = (__bf16*)alloc((size_t)cN2 * 128 * 2);
  __bf16* f4b  = (__bf16*)alloc((size_t)cN2 * 256 * 2);
  __bf16* f5b  = (__bf16*)alloc((size_t)cN1 * 128 * 2);
  float*  f6   = (float*)alloc((size_t)cN0 * 32 * 4);
  __bf16* WT2  = (__bf16*)alloc(960 * 64 * 2);
  __bf16* WT3  = (__bf16*)alloc(960 * 128 * 2);
  __bf16* WT4  = (__bf16*)alloc(1920 * 128 * 2);
  __bf16* WT5  = (__bf16*)alloc(1920 * 256 * 2);
  __bf16* WTu1 = (__bf16*)alloc(384 * 128 * 2);
  __bf16* WTu2 = (__bf16*)alloc(192 * 32 * 2);
  unsigned* gm = (unsigned*)alloc(256);
  float4* pk0  = (float4*)alloc((size_t)cN0 * 16);
  float4* pk1  = (float4*)alloc((size_t)cN1 * 16);
  float4* pk2  = (float4*)alloc((size_t)cN2 * 16);

  prep_kernel<<<dim3(240, 9), 256, 0, stream>>>(
      points0, features, points1, points2, W2, W3, W4, W5, Wu1, Wu2,
      pk0, pk1, pk2, WT2, WT3, WT4, WT5, WTu1, WTu2, gm);
  kpconv_l1<<<cN0 / 32, 512, 0, stream>>>(pk0, neighbors0, kpoints, W1, f0b, R0);

  // L2: strided, f0 -> f1 [N1,64]
  kpconv_fused<64, 64, 32, true><<<(cN1 + 31) / 32, 512, 0, stream>>>(
      pk1, pk0, pools0, f0b, kpoints, WT2, f1b, cN1, R0);
  // L3: simple, f1 -> f2 [N1,128]
  kpconv_fused<64, 128, 32, false><<<(cN1 + 31) / 32, 512, 0, stream>>>(
      pk1, pk1, neighbors1, f1b, kpoints, WT3, f2b, cN1, 2.f * R0);
  // L4: strided, f2 -> f3 [N2,128]
  kpconv_fused<128, 128, 16, true><<<(cN2 + 15) / 16, 512, 0, stream>>>(
      pk2, pk1, pools1, f2b, kpoints, WT4, f3b, cN2, 2.f * R0);
  // L5: simple, f3 -> f4 [N2,256]
  kpconv_fused<128, 256, 16, false><<<(cN2 + 15) / 16, 512, 0, stream>>>(
      pk2, pk2, neighbors2, f3b, kpoints, WT5, f4b, cN2, 4.f * R0);

  // D1: f5 = leaky(concat(f4[up1], f2) @ Wu1)
  gemm_mfma<true, true><<<dim3(2, 235), 256, 0, stream>>>(
      f4b, f2b, upsamples1, 256, WTu1, f5b, cN1, 128, 384);
  // D2: f6 (f32) = concat(f5[up0], f0) @ Wu2, fused global max
  d2_kernel<<<(cN0 + 127) / 128, 256, 0, stream>>>(
      f5b, f0b, upsamples0, WTu2, f6, cN0, gm);

  float* out_fnorm = (float*)d_out;
  float* out_scores = out_fnorm + (size_t)cN0 * 32;
  detect_kernel<<<(cN0 + 15) / 16, 512, 0, stream>>>(f6, neighbors0, (const float*)gm,
                                                     out_fnorm, out_scores, cN0);
}